// Round 8
// baseline (322.865 us; speedup 1.0000x reference)
//
#include <hip/hip_runtime.h>

typedef unsigned short u16;
typedef __attribute__((ext_vector_type(8))) short short8;
typedef __attribute__((ext_vector_type(4))) unsigned short u16x4;
typedef __attribute__((ext_vector_type(4))) float f32x4;

#define N_TOKENS 32768
#define EMBED 512
#define NCLS 16
#define NBATCH 8
#define NHEAD 8
#define DHEAD 64

__device__ __forceinline__ u16 f2bf(float f) {
  unsigned u = __float_as_uint(f);
  u += 0x7fffu + ((u >> 16) & 1u);   // RNE
  return (u16)(u >> 16);
}

__device__ __forceinline__ void async16(const u16* g, u16* l) {
  __builtin_amdgcn_global_load_lds(
      (__attribute__((address_space(1))) const unsigned int*)(const void*)g,
      (__attribute__((address_space(3))) unsigned int*)(void*)l,
      16, 0, 0);
}

// ---------------- fp32 -> bf16 converter (4 elems/thread, streaming) ----------------
__global__ __launch_bounds__(256) void cvt_bf16(const float4* __restrict__ in,
                                                u16x4* __restrict__ out, int n4) {
  int i = blockIdx.x * blockDim.x + threadIdx.x;
  if (i >= n4) return;
  float4 v = in[i];
  u16x4 o;
  o[0] = f2bf(v.x); o[1] = f2bf(v.y); o[2] = f2bf(v.z); o[3] = f2bf(v.w);
  out[i] = o;
}

// ---------------- K/V projection, W-stationary (r6, passing) ----------------
__global__ __launch_bounds__(256) void kvproj_kernel(
    const float* __restrict__ key, const float* __restrict__ val,
    const float* __restrict__ Wk, const float* __restrict__ bk,
    const float* __restrict__ Wv, const float* __restrict__ bv,
    float* __restrict__ kproj, float* __restrict__ vproj) {
  const int tid = threadIdx.x;
  const bool isV = blockIdx.x & 1;
  const int fgrp = blockIdx.x >> 1;           // [0,128)
  const int wave = tid >> 6;
  const int ec = tid & 63;
  const int fr = fgrp * 4 + wave;             // [0,512)
  const float* W = (isV ? Wv : Wk) + (size_t)fr * 512 + ec * 8;
  const float4 w0 = *(const float4*)W;
  const float4 w1 = *(const float4*)(W + 4);
  const float* src = isV ? val : key;
  const float bval = (isV ? bv : bk)[fr];
  const int h = fr >> 6, d = fr & 63;

#pragma unroll 4
  for (int r = 0; r < 128; r++) {
    const int b = r >> 4, l = r & 15;
    const float* s = src + (size_t)l * (NBATCH * EMBED) + (size_t)b * EMBED + ec * 8;
    float4 a0 = *(const float4*)s;
    float4 a1 = *(const float4*)(s + 4);
    float acc = a0.x * w0.x + a0.y * w0.y + a0.z * w0.z + a0.w * w0.w +
                a1.x * w1.x + a1.y * w1.y + a1.z * w1.z + a1.w * w1.w;
    acc += __shfl_xor(acc, 1);
    acc += __shfl_xor(acc, 2);
    acc += __shfl_xor(acc, 4);
    acc += __shfl_xor(acc, 8);
    acc += __shfl_xor(acc, 16);
    acc += __shfl_xor(acc, 32);
    if (ec == 0) {
      acc += bval;
      if (!isV) kproj[((size_t)(b * EMBED + fr)) * NCLS + l] = acc;
      else      vproj[(size_t)b * 8192 + (size_t)h * 1024 + l * 64 + d] = acc;
    }
  }
}

// ---------------- merged build: Kq / WoV / sb (r6, passing) ----------------
__global__ __launch_bounds__(256) void build_all(
    const float* __restrict__ kproj, const float* __restrict__ vproj,
    const float* __restrict__ Wq, const float* __restrict__ bq,
    const float* __restrict__ Wo,
    u16* __restrict__ Kqb, u16* __restrict__ WoVb, float* __restrict__ sb) {
  const int blk = blockIdx.x;
  if (blk < 2048) {
    int t = blk * 256 + threadIdx.x;   // 8*128*512
    int e = t & 511;
    int hl = (t >> 9) & 127;
    int b = t >> 16;
    int h = hl >> 4, l = hl & 15;
    const float* kp = kproj + (size_t)b * 8192 + h * 1024 + l;
    const float* wq = Wq + (size_t)(h * 64) * 512 + e;
    float acc = 0.f;
#pragma unroll 16
    for (int d = 0; d < 64; d++) acc += kp[d * 16] * wq[d * 512];
    Kqb[t] = f2bf(acc);
  } else if (blk < 3072) {
    const int wave = threadIdx.x >> 6;
    const int lane = threadIdx.x & 63;
    const int wgid = (blk - 2048) * 4 + wave;   // [0,4096)
    const int b = wgid >> 9, f = wgid & 511;
    const int l = lane >> 2, c = lane & 3;
    const float* vp = vproj + (size_t)b * 8192 + l * 64 + c * 16;
    const float* wo = Wo + (size_t)f * 512 + c * 16;
#pragma unroll 2
    for (int h = 0; h < 8; h++) {
      const float* v = vp + h * 1024;
      const float* w = wo + h * 64;
      float4 v0 = *(const float4*)v,       w0 = *(const float4*)w;
      float4 v1 = *(const float4*)(v + 4), w1 = *(const float4*)(w + 4);
      float4 v2 = *(const float4*)(v + 8), w2 = *(const float4*)(w + 8);
      float4 v3 = *(const float4*)(v + 12), w3 = *(const float4*)(w + 12);
      float acc = v0.x * w0.x + v0.y * w0.y + v0.z * w0.z + v0.w * w0.w +
                  v1.x * w1.x + v1.y * w1.y + v1.z * w1.z + v1.w * w1.w +
                  v2.x * w2.x + v2.y * w2.y + v2.z * w2.z + v2.w * w2.w +
                  v3.x * w3.x + v3.y * w3.y + v3.z * w3.z + v3.w * w3.w;
      acc += __shfl_xor(acc, 1);
      acc += __shfl_xor(acc, 2);
      if (c == 0) WoVb[(size_t)b * 65536 + (size_t)f * 128 + h * 16 + l] = f2bf(acc);
    }
  } else {
    int t = (blk - 3072) * 256 + threadIdx.x;   // 1024
    int hl = t & 127, b = t >> 7;
    int h = hl >> 4, l = hl & 15;
    const float* kp = kproj + (size_t)b * 8192 + h * 1024 + l;
    const float* q = bq + h * 64;
    float acc = 0.f;
#pragma unroll
    for (int d = 0; d < 64; d++) acc += q[d] * kp[d * 16];
    sb[t] = acc;
  }
}

// ---------------- fused: scores GEMM + softmax + out GEMM ----------------
// v8 = v5 (proven-best 100us: per-step __syncthreads dbuf, uncapped regs,
// tail-split grid) with exactly three deltas:
//  1. A reads bf16 qbf (one short8/step, L3-warm) -- cvt kernel restored;
//     the fp32 loads + 8-elem f2bf chain leave the barrier->MFMA critical path.
//  2. s_setprio(1) around the MFMA clusters (T5: pays when co-resident blocks
//     are at different phases).
//  3. No inline-asm waits anywhere (r7 proved they fight the compiler).
__global__ __launch_bounds__(256) void fused_attn(
    const u16* __restrict__ A, const u16* __restrict__ Kqb,
    const u16* __restrict__ WoVb, const float* __restrict__ sb,
    const float* __restrict__ bo, const int* __restrict__ bidx,
    float* __restrict__ out) {
  __shared__ __align__(16) u16 Bs[2][128 * 32];   // 16 KB: Kq k-slice, dbuf
  __shared__ __align__(16) u16 Ps[64 * 128];      // 16 KB: P, XOR-swizzled
  const int tid = threadIdx.x;
  const int lane = tid & 63;
  const int wave = tid >> 6;
  const int quad = lane >> 4;
  const int l16 = lane & 15;
  const int tileId = blockIdx.x >> 1;
  const int slot = blockIdx.x & 1;
  const int m0 = tileId * 64;
  const int bFirst = bidx[m0];
  const int bLast = bidx[m0 + 63];
  if (slot == 1 && bFirst == bLast) return;   // uniform exit, before any barrier
  const int b0 = (slot == 0) ? bFirst : bFirst + 1;
  const int b1 = (slot == 0) ? bFirst : bLast;

  // staging coords: 512 chunks of 16B per 8KB k-slice; thread owns chunks
  // tid and tid+256. chunk c -> row=c>>2, kpart=c&3; source pre-swizzled.
  const int r0 = tid >> 2, r1 = r0 + 64;
  const int lg0 = (tid & 3) ^ ((r0 >> 1) & 3);
  const int lg1 = (tid & 3) ^ ((r1 >> 1) & 3);
  const size_t boff0 = (size_t)r0 * 512 + lg0 * 8;
  const size_t boff1 = (size_t)r1 * 512 + lg1 * 8;

  // per-row batch for predicated stores (phase 2: wave covers all 64 rows)
  int rowb[4][4];
#pragma unroll
  for (int mi = 0; mi < 4; mi++)
#pragma unroll
    for (int r = 0; r < 4; r++) rowb[mi][r] = bidx[m0 + mi * 16 + quad * 4 + r];

  // phase-1 A pointer: wave-exclusive row, quad picks 8-elem k-slice (bf16)
  const u16* pA = A + (size_t)(m0 + wave * 16 + l16) * 512 + quad * 8;

  for (int bb = b0; bb <= b1; bb++) {
    const u16* Bq = Kqb + (size_t)bb * 65536;

    // prologue: stage k-slice 0 into buf 0; prefetch A slice 0
    async16(Bq + boff0, &Bs[0][tid * 8]);
    async16(Bq + boff1, &Bs[0][tid * 8 + 2048]);
    short8 aCur = *(const short8*)pA;

    f32x4 acc1[8];
#pragma unroll
    for (int j = 0; j < 8; j++) acc1[j] = (f32x4){0.f, 0.f, 0.f, 0.f};

    for (int t = 0; t < 16; t++) {
      __syncthreads();                     // drains vmcnt -> buf[t&1] + A(t) ready
      const int cur = t & 1;
      if (t < 15) {                        // stage next k-slice; overlaps MFMA below
        const int ko = (t + 1) * 32;
        async16(Bq + boff0 + ko, &Bs[cur ^ 1][tid * 8]);
        async16(Bq + boff1 + ko, &Bs[cur ^ 1][tid * 8 + 2048]);
      }
      short8 af = aCur;
      if (t < 15) aCur = *(const short8*)(pA + (t + 1) * 32);   // prefetch A(t+1)
      __builtin_amdgcn_s_setprio(1);
#pragma unroll
      for (int ni = 0; ni < 8; ni++) {
        const int rw = ni * 16 + l16;
        short8 bfr = *(const short8*)&Bs[cur][rw * 32 + ((quad ^ ((rw >> 1) & 3)) << 3)];
        acc1[ni] = __builtin_amdgcn_mfma_f32_16x16x32_bf16(af, bfr, acc1[ni], 0, 0, 0);
      }
      __builtin_amdgcn_s_setprio(0);
    }

    // ---- softmax over each head's 16 l-cols (16-lane shfl), P -> LDS ----
    float sbv[8];
#pragma unroll
    for (int ni = 0; ni < 8; ni++) sbv[ni] = sb[bb * 128 + ni * 16 + l16];
#pragma unroll
    for (int r = 0; r < 4; r++) {
      const int row = wave * 16 + quad * 4 + r;   // wave-exclusive rows
#pragma unroll
      for (int ni = 0; ni < 8; ni++) {
        float v = acc1[ni][r] + sbv[ni];
        float mx = v;
        mx = fmaxf(mx, __shfl_xor(mx, 1));
        mx = fmaxf(mx, __shfl_xor(mx, 2));
        mx = fmaxf(mx, __shfl_xor(mx, 4));
        mx = fmaxf(mx, __shfl_xor(mx, 8));
        float ev = __expf((v - mx) * 0.125f);   // scale = D^-0.5
        float s = ev;
        s += __shfl_xor(s, 1);
        s += __shfl_xor(s, 2);
        s += __shfl_xor(s, 4);
        s += __shfl_xor(s, 8);
        const int col = ni * 16 + l16;
        Ps[row * 128 + (((col >> 3) ^ (row & 7)) << 3) + (col & 7)] = f2bf(ev / s);
      }
    }
    __syncthreads();   // all P stripes visible

    // ---- phase 2: out[64,512] = P x WoV[bb]^T; wave owns 128 f-cols ----
    const u16* Wv = WoVb + (size_t)bb * 65536;
#pragma unroll
    for (int h2 = 0; h2 < 2; h2++) {
      const int f0 = wave * 128 + h2 * 64;
      f32x4 acc2[4][4];
#pragma unroll
      for (int i = 0; i < 4; i++)
#pragma unroll
        for (int j = 0; j < 4; j++) acc2[i][j] = (f32x4){0.f, 0.f, 0.f, 0.f};
#pragma unroll
      for (int kk = 0; kk < 4; kk++) {
        short8 paf[4], bf2[4];
#pragma unroll
        for (int mi = 0; mi < 4; mi++) {
          const int row = mi * 16 + l16;
          paf[mi] = *(const short8*)&Ps[row * 128 + (((kk * 4 + quad) ^ (row & 7)) << 3)];
        }
#pragma unroll
        for (int ni = 0; ni < 4; ni++) {
          const int fr = f0 + ni * 16 + l16;
          bf2[ni] = *(const short8*)(Wv + (size_t)fr * 128 + kk * 32 + quad * 8);
        }
        __builtin_amdgcn_s_setprio(1);
#pragma unroll
        for (int mi = 0; mi < 4; mi++)
#pragma unroll
          for (int ni = 0; ni < 4; ni++)
            acc2[mi][ni] = __builtin_amdgcn_mfma_f32_16x16x32_bf16(paf[mi], bf2[ni], acc2[mi][ni], 0, 0, 0);
        __builtin_amdgcn_s_setprio(0);
      }
      float bov[4];
#pragma unroll
      for (int ni = 0; ni < 4; ni++) bov[ni] = bo[f0 + ni * 16 + l16];
#pragma unroll
      for (int mi = 0; mi < 4; mi++)
#pragma unroll
        for (int r = 0; r < 4; r++) {
          if (rowb[mi][r] == bb) {
            const size_t row = m0 + mi * 16 + quad * 4 + r;
#pragma unroll
            for (int ni = 0; ni < 4; ni++)
              out[row * 512 + f0 + ni * 16 + l16] = acc2[mi][ni][r] + bov[ni];
          }
        }
    }
    __syncthreads();   // Ps/Bs safe to overwrite next bb
  }
}

extern "C" void kernel_launch(void* const* d_in, const int* in_sizes, int n_in,
                              void* d_out, int out_size, void* d_ws, size_t ws_size,
                              hipStream_t stream) {
  const float* query = (const float*)d_in[0];
  const float* keyt = (const float*)d_in[1];
  const float* valt = (const float*)d_in[2];
  const int* bidx = (const int*)d_in[3];
  // d_in[4] = batch_size (scalar, fixed = 8)
  const float* Wq = (const float*)d_in[5];
  const float* bq = (const float*)d_in[6];
  const float* Wk = (const float*)d_in[7];
  const float* bk = (const float*)d_in[8];
  const float* Wv = (const float*)d_in[9];
  const float* bv = (const float*)d_in[10];
  const float* Wo = (const float*)d_in[11];
  const float* bo = (const float*)d_in[12];
  float* out = (float*)d_out;

  // workspace layout (bytes)
  unsigned char* w = (unsigned char*)d_ws;
  u16* qbf = (u16*)(w);                       // 33,554,432: query bf16 [N,E]
  float* kproj = (float*)(w + 41943040ull);   //    262,144: [B,H,D,L]
  float* vproj = (float*)(w + 42205184ull);   //    262,144: [B,H,L,D]
  u16* Kqb = (u16*)(w + 42467328ull);         //  1,048,576: [B,128,512] bf16
  u16* WoVb = (u16*)(w + 43515904ull);        //  1,048,576: [B,512,128] bf16
  float* sb = (float*)(w + 44564480ull);      //      4,096: [B,128]

  // 1) query -> bf16 (streaming, ~full BW)
  cvt_bf16<<<N_TOKENS * EMBED / 4 / 256, 256, 0, stream>>>(
      (const float4*)query, (u16x4*)qbf, N_TOKENS * EMBED / 4);

  // 2) K/V projections (fp32, W-stationary)
  kvproj_kernel<<<256, 256, 0, stream>>>(keyt, valt, Wk, bk, Wv, bv, kproj, vproj);

  // 3) fold Wq through k, Wo through v, and sb — one launch
  build_all<<<3076, 256, 0, stream>>>(kproj, vproj, Wq, bq, Wo, Kqb, WoVb, sb);

  // 4) fused: scores -> softmax -> out (tail-split grid)
  fused_attn<<<N_TOKENS / 64 * 2, 256, 0, stream>>>(qbf, Kqb, WoVb, sb, bo, bidx, out);
}

// Round 9
// 288.845 us; speedup vs baseline: 1.1178x; 1.1178x over previous
//
#include <hip/hip_runtime.h>

typedef unsigned short u16;
typedef __attribute__((ext_vector_type(8))) short short8;
typedef __attribute__((ext_vector_type(4))) unsigned short u16x4;
typedef __attribute__((ext_vector_type(4))) float f32x4;

#define N_TOKENS 32768
#define EMBED 512
#define NCLS 16
#define NBATCH 8
#define NHEAD 8
#define DHEAD 64

__device__ __forceinline__ u16 f2bf(float f) {
  unsigned u = __float_as_uint(f);
  u += 0x7fffu + ((u >> 16) & 1u);   // RNE
  return (u16)(u >> 16);
}

__device__ __forceinline__ void async16(const u16* g, u16* l) {
  __builtin_amdgcn_global_load_lds(
      (__attribute__((address_space(1))) const unsigned int*)(const void*)g,
      (__attribute__((address_space(3))) unsigned int*)(void*)l,
      16, 0, 0);
}

// ---------------- K/V projection, W-stationary (r6, passing) ----------------
__global__ __launch_bounds__(256) void kvproj_kernel(
    const float* __restrict__ key, const float* __restrict__ val,
    const float* __restrict__ Wk, const float* __restrict__ bk,
    const float* __restrict__ Wv, const float* __restrict__ bv,
    float* __restrict__ kproj, float* __restrict__ vproj) {
  const int tid = threadIdx.x;
  const bool isV = blockIdx.x & 1;
  const int fgrp = blockIdx.x >> 1;           // [0,128)
  const int wave = tid >> 6;
  const int ec = tid & 63;
  const int fr = fgrp * 4 + wave;             // [0,512)
  const float* W = (isV ? Wv : Wk) + (size_t)fr * 512 + ec * 8;
  const float4 w0 = *(const float4*)W;
  const float4 w1 = *(const float4*)(W + 4);
  const float* src = isV ? val : key;
  const float bval = (isV ? bv : bk)[fr];
  const int h = fr >> 6, d = fr & 63;

#pragma unroll 4
  for (int r = 0; r < 128; r++) {
    const int b = r >> 4, l = r & 15;
    const float* s = src + (size_t)l * (NBATCH * EMBED) + (size_t)b * EMBED + ec * 8;
    float4 a0 = *(const float4*)s;
    float4 a1 = *(const float4*)(s + 4);
    float acc = a0.x * w0.x + a0.y * w0.y + a0.z * w0.z + a0.w * w0.w +
                a1.x * w1.x + a1.y * w1.y + a1.z * w1.z + a1.w * w1.w;
    acc += __shfl_xor(acc, 1);
    acc += __shfl_xor(acc, 2);
    acc += __shfl_xor(acc, 4);
    acc += __shfl_xor(acc, 8);
    acc += __shfl_xor(acc, 16);
    acc += __shfl_xor(acc, 32);
    if (ec == 0) {
      acc += bval;
      if (!isV) kproj[((size_t)(b * EMBED + fr)) * NCLS + l] = acc;
      else      vproj[(size_t)b * 8192 + (size_t)h * 1024 + l * 64 + d] = acc;
    }
  }
}

// ---------------- merged build: Kq / WoV / sb (r6, passing) ----------------
__global__ __launch_bounds__(256) void build_all(
    const float* __restrict__ kproj, const float* __restrict__ vproj,
    const float* __restrict__ Wq, const float* __restrict__ bq,
    const float* __restrict__ Wo,
    u16* __restrict__ Kqb, u16* __restrict__ WoVb, float* __restrict__ sb) {
  const int blk = blockIdx.x;
  if (blk < 2048) {
    int t = blk * 256 + threadIdx.x;   // 8*128*512
    int e = t & 511;
    int hl = (t >> 9) & 127;
    int b = t >> 16;
    int h = hl >> 4, l = hl & 15;
    const float* kp = kproj + (size_t)b * 8192 + h * 1024 + l;
    const float* wq = Wq + (size_t)(h * 64) * 512 + e;
    float acc = 0.f;
#pragma unroll 16
    for (int d = 0; d < 64; d++) acc += kp[d * 16] * wq[d * 512];
    Kqb[t] = f2bf(acc);
  } else if (blk < 3072) {
    const int wave = threadIdx.x >> 6;
    const int lane = threadIdx.x & 63;
    const int wgid = (blk - 2048) * 4 + wave;   // [0,4096)
    const int b = wgid >> 9, f = wgid & 511;
    const int l = lane >> 2, c = lane & 3;
    const float* vp = vproj + (size_t)b * 8192 + l * 64 + c * 16;
    const float* wo = Wo + (size_t)f * 512 + c * 16;
#pragma unroll 2
    for (int h = 0; h < 8; h++) {
      const float* v = vp + h * 1024;
      const float* w = wo + h * 64;
      float4 v0 = *(const float4*)v,       w0 = *(const float4*)w;
      float4 v1 = *(const float4*)(v + 4), w1 = *(const float4*)(w + 4);
      float4 v2 = *(const float4*)(v + 8), w2 = *(const float4*)(w + 8);
      float4 v3 = *(const float4*)(v + 12), w3 = *(const float4*)(w + 12);
      float acc = v0.x * w0.x + v0.y * w0.y + v0.z * w0.z + v0.w * w0.w +
                  v1.x * w1.x + v1.y * w1.y + v1.z * w1.z + v1.w * w1.w +
                  v2.x * w2.x + v2.y * w2.y + v2.z * w2.z + v2.w * w2.w +
                  v3.x * w3.x + v3.y * w3.y + v3.z * w3.z + v3.w * w3.w;
      acc += __shfl_xor(acc, 1);
      acc += __shfl_xor(acc, 2);
      if (c == 0) WoVb[(size_t)b * 65536 + (size_t)f * 128 + h * 16 + l] = f2bf(acc);
    }
  } else {
    int t = (blk - 3072) * 256 + threadIdx.x;   // 1024
    int hl = t & 127, b = t >> 7;
    int h = hl >> 4, l = hl & 15;
    const float* kp = kproj + (size_t)b * 8192 + h * 1024 + l;
    const float* q = bq + h * 64;
    float acc = 0.f;
#pragma unroll
    for (int d = 0; d < 64; d++) acc += q[d] * kp[d * 16];
    sb[t] = acc;
  }
}

// ---------------- fused: scores GEMM + softmax + out GEMM ----------------
// v9 = v8 (91us: per-step __syncthreads dbuf, uncapped, tail-split, setprio)
// with two deltas:
//  1. BK 32->64: 8 K-steps instead of 16. Halves the latency-dominated
//     barrier windows; 16 MFMA/wave/step instead of 8. B tile [128][64] bf16
//     = 16 KB/slice, XOR-swizzled at 16B-chunk granularity: LDS[r][pc] holds
//     global chunk pc^(r&7)  (2-way bank aliasing on reads = free).
//  2. A reads fp32 query directly (cvt kernel DELETED: -96 MB HBM, -1 launch).
//     A(t+1) prefetched before the MFMA cluster; f2bf runs between prefetch
//     and MFMAs, off the load-critical path.
__global__ __launch_bounds__(256) void fused_attn(
    const float* __restrict__ query, const u16* __restrict__ Kqb,
    const u16* __restrict__ WoVb, const float* __restrict__ sb,
    const float* __restrict__ bo, const int* __restrict__ bidx,
    float* __restrict__ out) {
  __shared__ __align__(16) u16 Bs[2][128 * 64];   // 32 KB: Kq k-slice, dbuf
  __shared__ __align__(16) u16 Ps[64 * 128];      // 16 KB: P, XOR-swizzled
  const int tid = threadIdx.x;
  const int lane = tid & 63;
  const int wave = tid >> 6;
  const int quad = lane >> 4;
  const int l16 = lane & 15;
  const int tileId = blockIdx.x >> 1;
  const int slot = blockIdx.x & 1;
  const int m0 = tileId * 64;
  const int bFirst = bidx[m0];
  const int bLast = bidx[m0 + 63];
  if (slot == 1 && bFirst == bLast) return;   // uniform exit, before any barrier
  const int b0 = (slot == 0) ? bFirst : bFirst + 1;
  const int b1 = (slot == 0) ? bFirst : bLast;

  // staging coords (BK=64): 1024 chunks of 16B per 16KB slice; thread owns
  // chunks c_i = tid + i*256 (i=0..3). c -> row=c>>3, physchunk=c&7.
  // Both (c&7) and ((c>>3)&7) are i-invariant -> one base, stride 32 rows.
  const int rB = tid >> 3;                       // row of chunk 0
  const int lgB = (tid & 7) ^ (rB & 7);          // global chunk for phys (tid&7)
  const size_t bbase = (size_t)rB * 512 + lgB * 8;   // u16 elems; +i*32*512

  // per-row batch for predicated stores (phase 2: wave covers all 64 rows)
  int rowb[4][4];
#pragma unroll
  for (int mi = 0; mi < 4; mi++)
#pragma unroll
    for (int r = 0; r < 4; r++) rowb[mi][r] = bidx[m0 + mi * 16 + quad * 4 + r];

  // phase-1 A pointer: wave-exclusive row (fp32), quad picks 8-elem sub-slice
  const float* pA = query + (size_t)(m0 + wave * 16 + l16) * 512 + quad * 8;

  for (int bb = b0; bb <= b1; bb++) {
    const u16* Bq = Kqb + (size_t)bb * 65536;

    // prologue: stage k-slice 0 into buf 0; load A slice 0 (fp32)
#pragma unroll
    for (int i = 0; i < 4; i++)
      async16(Bq + bbase + (size_t)i * 32 * 512, &Bs[0][(tid + i * 256) * 8]);
    float4 aC[4];
    aC[0] = *(const float4*)(pA);
    aC[1] = *(const float4*)(pA + 4);
    aC[2] = *(const float4*)(pA + 32);
    aC[3] = *(const float4*)(pA + 36);

    f32x4 acc1[8];
#pragma unroll
    for (int j = 0; j < 8; j++) acc1[j] = (f32x4){0.f, 0.f, 0.f, 0.f};

    for (int t = 0; t < 8; t++) {
      __syncthreads();                     // drains vmcnt -> buf[t&1] + A(t) ready
      const int cur = t & 1;
      if (t < 7) {                         // stage next k-slice; overlaps MFMA below
        const size_t ko = (size_t)(t + 1) * 64;
#pragma unroll
        for (int i = 0; i < 4; i++)
          async16(Bq + bbase + ko + (size_t)i * 32 * 512, &Bs[cur ^ 1][(tid + i * 256) * 8]);
      }
      float4 a0 = aC[0], a1 = aC[1], a2 = aC[2], a3 = aC[3];
      if (t < 7) {                         // prefetch A(t+1)
        const float* p = pA + (t + 1) * 64;
        aC[0] = *(const float4*)(p);
        aC[1] = *(const float4*)(p + 4);
        aC[2] = *(const float4*)(p + 32);
        aC[3] = *(const float4*)(p + 36);
      }
      short8 af[2];
      af[0][0] = (short)f2bf(a0.x); af[0][1] = (short)f2bf(a0.y);
      af[0][2] = (short)f2bf(a0.z); af[0][3] = (short)f2bf(a0.w);
      af[0][4] = (short)f2bf(a1.x); af[0][5] = (short)f2bf(a1.y);
      af[0][6] = (short)f2bf(a1.z); af[0][7] = (short)f2bf(a1.w);
      af[1][0] = (short)f2bf(a2.x); af[1][1] = (short)f2bf(a2.y);
      af[1][2] = (short)f2bf(a2.z); af[1][3] = (short)f2bf(a2.w);
      af[1][4] = (short)f2bf(a3.x); af[1][5] = (short)f2bf(a3.y);
      af[1][6] = (short)f2bf(a3.z); af[1][7] = (short)f2bf(a3.w);
      __builtin_amdgcn_s_setprio(1);
#pragma unroll
      for (int kk = 0; kk < 2; kk++) {
#pragma unroll
        for (int ni = 0; ni < 8; ni++) {
          const int rw = ni * 16 + l16;
          const int phys = (kk * 4 + quad) ^ (rw & 7);
          short8 bfr = *(const short8*)&Bs[cur][rw * 64 + phys * 8];
          acc1[ni] = __builtin_amdgcn_mfma_f32_16x16x32_bf16(af[kk], bfr, acc1[ni], 0, 0, 0);
        }
      }
      __builtin_amdgcn_s_setprio(0);
    }

    // ---- softmax over each head's 16 l-cols (16-lane shfl), P -> LDS ----
    float sbv[8];
#pragma unroll
    for (int ni = 0; ni < 8; ni++) sbv[ni] = sb[bb * 128 + ni * 16 + l16];
#pragma unroll
    for (int r = 0; r < 4; r++) {
      const int row = wave * 16 + quad * 4 + r;   // wave-exclusive rows
#pragma unroll
      for (int ni = 0; ni < 8; ni++) {
        float v = acc1[ni][r] + sbv[ni];
        float mx = v;
        mx = fmaxf(mx, __shfl_xor(mx, 1));
        mx = fmaxf(mx, __shfl_xor(mx, 2));
        mx = fmaxf(mx, __shfl_xor(mx, 4));
        mx = fmaxf(mx, __shfl_xor(mx, 8));
        float ev = __expf((v - mx) * 0.125f);   // scale = D^-0.5
        float s = ev;
        s += __shfl_xor(s, 1);
        s += __shfl_xor(s, 2);
        s += __shfl_xor(s, 4);
        s += __shfl_xor(s, 8);
        const int col = ni * 16 + l16;
        Ps[row * 128 + (((col >> 3) ^ (row & 7)) << 3) + (col & 7)] = f2bf(ev / s);
      }
    }
    __syncthreads();   // all P stripes visible

    // ---- phase 2: out[64,512] = P x WoV[bb]^T; wave owns 128 f-cols ----
    const u16* Wv = WoVb + (size_t)bb * 65536;
#pragma unroll
    for (int h2 = 0; h2 < 2; h2++) {
      const int f0 = wave * 128 + h2 * 64;
      f32x4 acc2[4][4];
#pragma unroll
      for (int i = 0; i < 4; i++)
#pragma unroll
        for (int j = 0; j < 4; j++) acc2[i][j] = (f32x4){0.f, 0.f, 0.f, 0.f};
#pragma unroll
      for (int kk = 0; kk < 4; kk++) {
        short8 paf[4], bf2[4];
#pragma unroll
        for (int mi = 0; mi < 4; mi++) {
          const int row = mi * 16 + l16;
          paf[mi] = *(const short8*)&Ps[row * 128 + (((kk * 4 + quad) ^ (row & 7)) << 3)];
        }
#pragma unroll
        for (int ni = 0; ni < 4; ni++) {
          const int fr = f0 + ni * 16 + l16;
          bf2[ni] = *(const short8*)(Wv + (size_t)fr * 128 + kk * 32 + quad * 8);
        }
        __builtin_amdgcn_s_setprio(1);
#pragma unroll
        for (int mi = 0; mi < 4; mi++)
#pragma unroll
          for (int ni = 0; ni < 4; ni++)
            acc2[mi][ni] = __builtin_amdgcn_mfma_f32_16x16x32_bf16(paf[mi], bf2[ni], acc2[mi][ni], 0, 0, 0);
        __builtin_amdgcn_s_setprio(0);
      }
      float bov[4];
#pragma unroll
      for (int ni = 0; ni < 4; ni++) bov[ni] = bo[f0 + ni * 16 + l16];
#pragma unroll
      for (int mi = 0; mi < 4; mi++)
#pragma unroll
        for (int r = 0; r < 4; r++) {
          if (rowb[mi][r] == bb) {
            const size_t row = m0 + mi * 16 + quad * 4 + r;
#pragma unroll
            for (int ni = 0; ni < 4; ni++)
              out[row * 512 + f0 + ni * 16 + l16] = acc2[mi][ni][r] + bov[ni];
          }
        }
    }
    __syncthreads();   // Ps/Bs safe to overwrite next bb
  }
}

extern "C" void kernel_launch(void* const* d_in, const int* in_sizes, int n_in,
                              void* d_out, int out_size, void* d_ws, size_t ws_size,
                              hipStream_t stream) {
  const float* query = (const float*)d_in[0];
  const float* keyt = (const float*)d_in[1];
  const float* valt = (const float*)d_in[2];
  const int* bidx = (const int*)d_in[3];
  // d_in[4] = batch_size (scalar, fixed = 8)
  const float* Wq = (const float*)d_in[5];
  const float* bq = (const float*)d_in[6];
  const float* Wk = (const float*)d_in[7];
  const float* bk = (const float*)d_in[8];
  const float* Wv = (const float*)d_in[9];
  const float* bv = (const float*)d_in[10];
  const float* Wo = (const float*)d_in[11];
  const float* bo = (const float*)d_in[12];
  float* out = (float*)d_out;

  // workspace layout (bytes)
  unsigned char* w = (unsigned char*)d_ws;
  float* kproj = (float*)(w + 41943040ull);   //    262,144: [B,H,D,L]
  float* vproj = (float*)(w + 42205184ull);   //    262,144: [B,H,L,D]
  u16* Kqb = (u16*)(w + 42467328ull);         //  1,048,576: [B,128,512] bf16
  u16* WoVb = (u16*)(w + 43515904ull);        //  1,048,576: [B,512,128] bf16
  float* sb = (float*)(w + 44564480ull);      //      4,096: [B,128]

  // 1) K/V projections (fp32, W-stationary)
  kvproj_kernel<<<256, 256, 0, stream>>>(keyt, valt, Wk, bk, Wv, bv, kproj, vproj);

  // 2) fold Wq through k, Wo through v, and sb — one launch
  build_all<<<3076, 256, 0, stream>>>(kproj, vproj, Wq, bq, Wo, Kqb, WoVb, sb);

  // 3) fused: fp32 query -> scores -> softmax -> out (tail-split grid)
  fused_attn<<<N_TOKENS / 64 * 2, 256, 0, stream>>>(query, Kqb, WoVb, sb, bo, bidx, out);
}

// Round 10
// 271.061 us; speedup vs baseline: 1.1911x; 1.0656x over previous
//
#include <hip/hip_runtime.h>

typedef unsigned short u16;
typedef __attribute__((ext_vector_type(8))) short short8;
typedef __attribute__((ext_vector_type(4))) unsigned short u16x4;
typedef __attribute__((ext_vector_type(4))) float f32x4;

#define N_TOKENS 32768
#define EMBED 512
#define NCLS 16
#define NBATCH 8
#define NHEAD 8
#define DHEAD 64

__device__ __forceinline__ u16 f2bf(float f) {
  unsigned u = __float_as_uint(f);
  u += 0x7fffu + ((u >> 16) & 1u);   // RNE
  return (u16)(u >> 16);
}

__device__ __forceinline__ void async16(const u16* g, u16* l) {
  __builtin_amdgcn_global_load_lds(
      (__attribute__((address_space(1))) const unsigned int*)(const void*)g,
      (__attribute__((address_space(3))) unsigned int*)(void*)l,
      16, 0, 0);
}

// ---------------- K/V projection, W-stationary (r6, passing) ----------------
__global__ __launch_bounds__(256) void kvproj_kernel(
    const float* __restrict__ key, const float* __restrict__ val,
    const float* __restrict__ Wk, const float* __restrict__ bk,
    const float* __restrict__ Wv, const float* __restrict__ bv,
    float* __restrict__ kproj, float* __restrict__ vproj) {
  const int tid = threadIdx.x;
  const bool isV = blockIdx.x & 1;
  const int fgrp = blockIdx.x >> 1;           // [0,128)
  const int wave = tid >> 6;
  const int ec = tid & 63;
  const int fr = fgrp * 4 + wave;             // [0,512)
  const float* W = (isV ? Wv : Wk) + (size_t)fr * 512 + ec * 8;
  const float4 w0 = *(const float4*)W;
  const float4 w1 = *(const float4*)(W + 4);
  const float* src = isV ? val : key;
  const float bval = (isV ? bv : bk)[fr];
  const int h = fr >> 6, d = fr & 63;

#pragma unroll 4
  for (int r = 0; r < 128; r++) {
    const int b = r >> 4, l = r & 15;
    const float* s = src + (size_t)l * (NBATCH * EMBED) + (size_t)b * EMBED + ec * 8;
    float4 a0 = *(const float4*)s;
    float4 a1 = *(const float4*)(s + 4);
    float acc = a0.x * w0.x + a0.y * w0.y + a0.z * w0.z + a0.w * w0.w +
                a1.x * w1.x + a1.y * w1.y + a1.z * w1.z + a1.w * w1.w;
    acc += __shfl_xor(acc, 1);
    acc += __shfl_xor(acc, 2);
    acc += __shfl_xor(acc, 4);
    acc += __shfl_xor(acc, 8);
    acc += __shfl_xor(acc, 16);
    acc += __shfl_xor(acc, 32);
    if (ec == 0) {
      acc += bval;
      if (!isV) kproj[((size_t)(b * EMBED + fr)) * NCLS + l] = acc;
      else      vproj[(size_t)b * 8192 + (size_t)h * 1024 + l * 64 + d] = acc;
    }
  }
}

// ---------------- merged build: Kq / WoV / sb (r6, passing) ----------------
__global__ __launch_bounds__(256) void build_all(
    const float* __restrict__ kproj, const float* __restrict__ vproj,
    const float* __restrict__ Wq, const float* __restrict__ bq,
    const float* __restrict__ Wo,
    u16* __restrict__ Kqb, u16* __restrict__ WoVb, float* __restrict__ sb) {
  const int blk = blockIdx.x;
  if (blk < 2048) {
    int t = blk * 256 + threadIdx.x;   // 8*128*512
    int e = t & 511;
    int hl = (t >> 9) & 127;
    int b = t >> 16;
    int h = hl >> 4, l = hl & 15;
    const float* kp = kproj + (size_t)b * 8192 + h * 1024 + l;
    const float* wq = Wq + (size_t)(h * 64) * 512 + e;
    float acc = 0.f;
#pragma unroll 16
    for (int d = 0; d < 64; d++) acc += kp[d * 16] * wq[d * 512];
    Kqb[t] = f2bf(acc);
  } else if (blk < 3072) {
    const int wave = threadIdx.x >> 6;
    const int lane = threadIdx.x & 63;
    const int wgid = (blk - 2048) * 4 + wave;   // [0,4096)
    const int b = wgid >> 9, f = wgid & 511;
    const int l = lane >> 2, c = lane & 3;
    const float* vp = vproj + (size_t)b * 8192 + l * 64 + c * 16;
    const float* wo = Wo + (size_t)f * 512 + c * 16;
#pragma unroll 2
    for (int h = 0; h < 8; h++) {
      const float* v = vp + h * 1024;
      const float* w = wo + h * 64;
      float4 v0 = *(const float4*)v,       w0 = *(const float4*)w;
      float4 v1 = *(const float4*)(v + 4), w1 = *(const float4*)(w + 4);
      float4 v2 = *(const float4*)(v + 8), w2 = *(const float4*)(w + 8);
      float4 v3 = *(const float4*)(v + 12), w3 = *(const float4*)(w + 12);
      float acc = v0.x * w0.x + v0.y * w0.y + v0.z * w0.z + v0.w * w0.w +
                  v1.x * w1.x + v1.y * w1.y + v1.z * w1.z + v1.w * w1.w +
                  v2.x * w2.x + v2.y * w2.y + v2.z * w2.z + v2.w * w2.w +
                  v3.x * w3.x + v3.y * w3.y + v3.z * w3.z + v3.w * w3.w;
      acc += __shfl_xor(acc, 1);
      acc += __shfl_xor(acc, 2);
      if (c == 0) WoVb[(size_t)b * 65536 + (size_t)f * 128 + h * 16 + l] = f2bf(acc);
    }
  } else {
    int t = (blk - 3072) * 256 + threadIdx.x;   // 1024
    int hl = t & 127, b = t >> 7;
    int h = hl >> 4, l = hl & 15;
    const float* kp = kproj + (size_t)b * 8192 + h * 1024 + l;
    const float* q = bq + h * 64;
    float acc = 0.f;
#pragma unroll
    for (int d = 0; d < 64; d++) acc += q[d] * kp[d * 16];
    sb[t] = acc;
  }
}

// ---------------- fused: scores GEMM + softmax + out GEMM ----------------
// v10 = v9 with ONE delta: the tail-split slot moves from blockIdx LSB to the
// HIGH bit. MI355X round-robins workgroups over XCDs by blockIdx%8; with
// slot=blockIdx&1 every working (slot-0) block had even blockIdx -> all real
// work on XCDs {0,2,4,6} while {1,3,5,7} ran instant-exit blocks. Half the
// GPU idle since r5 (the 90-100us plateau, Occupancy ~5.5%). Now
// tileId=blockIdx&511, slot=blockIdx>>9: working blocks 0-511 stripe all 8
// XCDs; dead blocks 512-1023 dispatch after and exit in ~us.
__global__ __launch_bounds__(256) void fused_attn(
    const float* __restrict__ query, const u16* __restrict__ Kqb,
    const u16* __restrict__ WoVb, const float* __restrict__ sb,
    const float* __restrict__ bo, const int* __restrict__ bidx,
    float* __restrict__ out) {
  __shared__ __align__(16) u16 Bs[2][128 * 64];   // 32 KB: Kq k-slice, dbuf
  __shared__ __align__(16) u16 Ps[64 * 128];      // 16 KB: P, XOR-swizzled
  const int tid = threadIdx.x;
  const int lane = tid & 63;
  const int wave = tid >> 6;
  const int quad = lane >> 4;
  const int l16 = lane & 15;
  const int tileId = blockIdx.x & 511;    // v10: slot in HIGH bit (XCD parity fix)
  const int slot = blockIdx.x >> 9;
  const int m0 = tileId * 64;
  const int bFirst = bidx[m0];
  const int bLast = bidx[m0 + 63];
  if (slot == 1 && bFirst == bLast) return;   // uniform exit, before any barrier
  const int b0 = (slot == 0) ? bFirst : bFirst + 1;
  const int b1 = (slot == 0) ? bFirst : bLast;

  // staging coords (BK=64): 1024 chunks of 16B per 16KB slice; thread owns
  // chunks c_i = tid + i*256 (i=0..3). c -> row=c>>3, physchunk=c&7.
  // Both (c&7) and ((c>>3)&7) are i-invariant -> one base, stride 32 rows.
  const int rB = tid >> 3;                       // row of chunk 0
  const int lgB = (tid & 7) ^ (rB & 7);          // global chunk for phys (tid&7)
  const size_t bbase = (size_t)rB * 512 + lgB * 8;   // u16 elems; +i*32*512

  // per-row batch for predicated stores (phase 2: wave covers all 64 rows)
  int rowb[4][4];
#pragma unroll
  for (int mi = 0; mi < 4; mi++)
#pragma unroll
    for (int r = 0; r < 4; r++) rowb[mi][r] = bidx[m0 + mi * 16 + quad * 4 + r];

  // phase-1 A pointer: wave-exclusive row (fp32), quad picks 8-elem sub-slice
  const float* pA = query + (size_t)(m0 + wave * 16 + l16) * 512 + quad * 8;

  for (int bb = b0; bb <= b1; bb++) {
    const u16* Bq = Kqb + (size_t)bb * 65536;

    // prologue: stage k-slice 0 into buf 0; load A slice 0 (fp32)
#pragma unroll
    for (int i = 0; i < 4; i++)
      async16(Bq + bbase + (size_t)i * 32 * 512, &Bs[0][(tid + i * 256) * 8]);
    float4 aC[4];
    aC[0] = *(const float4*)(pA);
    aC[1] = *(const float4*)(pA + 4);
    aC[2] = *(const float4*)(pA + 32);
    aC[3] = *(const float4*)(pA + 36);

    f32x4 acc1[8];
#pragma unroll
    for (int j = 0; j < 8; j++) acc1[j] = (f32x4){0.f, 0.f, 0.f, 0.f};

    for (int t = 0; t < 8; t++) {
      __syncthreads();                     // drains vmcnt -> buf[t&1] + A(t) ready
      const int cur = t & 1;
      if (t < 7) {                         // stage next k-slice; overlaps MFMA below
        const size_t ko = (size_t)(t + 1) * 64;
#pragma unroll
        for (int i = 0; i < 4; i++)
          async16(Bq + bbase + ko + (size_t)i * 32 * 512, &Bs[cur ^ 1][(tid + i * 256) * 8]);
      }
      float4 a0 = aC[0], a1 = aC[1], a2 = aC[2], a3 = aC[3];
      if (t < 7) {                         // prefetch A(t+1)
        const float* p = pA + (t + 1) * 64;
        aC[0] = *(const float4*)(p);
        aC[1] = *(const float4*)(p + 4);
        aC[2] = *(const float4*)(p + 32);
        aC[3] = *(const float4*)(p + 36);
      }
      short8 af[2];
      af[0][0] = (short)f2bf(a0.x); af[0][1] = (short)f2bf(a0.y);
      af[0][2] = (short)f2bf(a0.z); af[0][3] = (short)f2bf(a0.w);
      af[0][4] = (short)f2bf(a1.x); af[0][5] = (short)f2bf(a1.y);
      af[0][6] = (short)f2bf(a1.z); af[0][7] = (short)f2bf(a1.w);
      af[1][0] = (short)f2bf(a2.x); af[1][1] = (short)f2bf(a2.y);
      af[1][2] = (short)f2bf(a2.z); af[1][3] = (short)f2bf(a2.w);
      af[1][4] = (short)f2bf(a3.x); af[1][5] = (short)f2bf(a3.y);
      af[1][6] = (short)f2bf(a3.z); af[1][7] = (short)f2bf(a3.w);
      __builtin_amdgcn_s_setprio(1);
#pragma unroll
      for (int kk = 0; kk < 2; kk++) {
#pragma unroll
        for (int ni = 0; ni < 8; ni++) {
          const int rw = ni * 16 + l16;
          const int phys = (kk * 4 + quad) ^ (rw & 7);
          short8 bfr = *(const short8*)&Bs[cur][rw * 64 + phys * 8];
          acc1[ni] = __builtin_amdgcn_mfma_f32_16x16x32_bf16(af[kk], bfr, acc1[ni], 0, 0, 0);
        }
      }
      __builtin_amdgcn_s_setprio(0);
    }

    // ---- softmax over each head's 16 l-cols (16-lane shfl), P -> LDS ----
    float sbv[8];
#pragma unroll
    for (int ni = 0; ni < 8; ni++) sbv[ni] = sb[bb * 128 + ni * 16 + l16];
#pragma unroll
    for (int r = 0; r < 4; r++) {
      const int row = wave * 16 + quad * 4 + r;   // wave-exclusive rows
#pragma unroll
      for (int ni = 0; ni < 8; ni++) {
        float v = acc1[ni][r] + sbv[ni];
        float mx = v;
        mx = fmaxf(mx, __shfl_xor(mx, 1));
        mx = fmaxf(mx, __shfl_xor(mx, 2));
        mx = fmaxf(mx, __shfl_xor(mx, 4));
        mx = fmaxf(mx, __shfl_xor(mx, 8));
        float ev = __expf((v - mx) * 0.125f);   // scale = D^-0.5
        float s = ev;
        s += __shfl_xor(s, 1);
        s += __shfl_xor(s, 2);
        s += __shfl_xor(s, 4);
        s += __shfl_xor(s, 8);
        const int col = ni * 16 + l16;
        Ps[row * 128 + (((col >> 3) ^ (row & 7)) << 3) + (col & 7)] = f2bf(ev / s);
      }
    }
    __syncthreads();   // all P stripes visible

    // ---- phase 2: out[64,512] = P x WoV[bb]^T; wave owns 128 f-cols ----
    const u16* Wv = WoVb + (size_t)bb * 65536;
#pragma unroll
    for (int h2 = 0; h2 < 2; h2++) {
      const int f0 = wave * 128 + h2 * 64;
      f32x4 acc2[4][4];
#pragma unroll
      for (int i = 0; i < 4; i++)
#pragma unroll
        for (int j = 0; j < 4; j++) acc2[i][j] = (f32x4){0.f, 0.f, 0.f, 0.f};
#pragma unroll
      for (int kk = 0; kk < 4; kk++) {
        short8 paf[4], bf2[4];
#pragma unroll
        for (int mi = 0; mi < 4; mi++) {
          const int row = mi * 16 + l16;
          paf[mi] = *(const short8*)&Ps[row * 128 + (((kk * 4 + quad) ^ (row & 7)) << 3)];
        }
#pragma unroll
        for (int ni = 0; ni < 4; ni++) {
          const int fr = f0 + ni * 16 + l16;
          bf2[ni] = *(const short8*)(Wv + (size_t)fr * 128 + kk * 32 + quad * 8);
        }
        __builtin_amdgcn_s_setprio(1);
#pragma unroll
        for (int mi = 0; mi < 4; mi++)
#pragma unroll
          for (int ni = 0; ni < 4; ni++)
            acc2[mi][ni] = __builtin_amdgcn_mfma_f32_16x16x32_bf16(paf[mi], bf2[ni], acc2[mi][ni], 0, 0, 0);
        __builtin_amdgcn_s_setprio(0);
      }
      float bov[4];
#pragma unroll
      for (int ni = 0; ni < 4; ni++) bov[ni] = bo[f0 + ni * 16 + l16];
#pragma unroll
      for (int mi = 0; mi < 4; mi++)
#pragma unroll
        for (int r = 0; r < 4; r++) {
          if (rowb[mi][r] == bb) {
            const size_t row = m0 + mi * 16 + quad * 4 + r;
#pragma unroll
            for (int ni = 0; ni < 4; ni++)
              out[row * 512 + f0 + ni * 16 + l16] = acc2[mi][ni][r] + bov[ni];
          }
        }
    }
    __syncthreads();   // Ps/Bs safe to overwrite next bb
  }
}

extern "C" void kernel_launch(void* const* d_in, const int* in_sizes, int n_in,
                              void* d_out, int out_size, void* d_ws, size_t ws_size,
                              hipStream_t stream) {
  const float* query = (const float*)d_in[0];
  const float* keyt = (const float*)d_in[1];
  const float* valt = (const float*)d_in[2];
  const int* bidx = (const int*)d_in[3];
  // d_in[4] = batch_size (scalar, fixed = 8)
  const float* Wq = (const float*)d_in[5];
  const float* bq = (const float*)d_in[6];
  const float* Wk = (const float*)d_in[7];
  const float* bk = (const float*)d_in[8];
  const float* Wv = (const float*)d_in[9];
  const float* bv = (const float*)d_in[10];
  const float* Wo = (const float*)d_in[11];
  const float* bo = (const float*)d_in[12];
  float* out = (float*)d_out;

  // workspace layout (bytes)
  unsigned char* w = (unsigned char*)d_ws;
  float* kproj = (float*)(w + 41943040ull);   //    262,144: [B,H,D,L]
  float* vproj = (float*)(w + 42205184ull);   //    262,144: [B,H,L,D]
  u16* Kqb = (u16*)(w + 42467328ull);         //  1,048,576: [B,128,512] bf16
  u16* WoVb = (u16*)(w + 43515904ull);        //  1,048,576: [B,512,128] bf16
  float* sb = (float*)(w + 44564480ull);      //      4,096: [B,128]

  // 1) K/V projections (fp32, W-stationary)
  kvproj_kernel<<<256, 256, 0, stream>>>(keyt, valt, Wk, bk, Wv, bv, kproj, vproj);

  // 2) fold Wq through k, Wo through v, and sb — one launch
  build_all<<<3076, 256, 0, stream>>>(kproj, vproj, Wq, bq, Wo, Kqb, WoVb, sb);

  // 3) fused: fp32 query -> scores -> softmax -> out (slot in HIGH bit)
  fused_attn<<<N_TOKENS / 64 * 2, 256, 0, stream>>>(query, Kqb, WoVb, sb, bo, bidx, out);
}

// Round 11
// 265.714 us; speedup vs baseline: 1.2151x; 1.0201x over previous
//
#include <hip/hip_runtime.h>

typedef unsigned short u16;
typedef __attribute__((ext_vector_type(8))) short short8;
typedef __attribute__((ext_vector_type(4))) unsigned short u16x4;
typedef __attribute__((ext_vector_type(4))) float f32x4;

#define N_TOKENS 32768
#define EMBED 512
#define NCLS 16
#define NBATCH 8
#define NHEAD 8
#define DHEAD 64

__device__ __forceinline__ u16 f2bf(float f) {
  unsigned u = __float_as_uint(f);
  u += 0x7fffu + ((u >> 16) & 1u);   // RNE
  return (u16)(u >> 16);
}

__device__ __forceinline__ void async16(const u16* g, u16* l) {
  __builtin_amdgcn_global_load_lds(
      (__attribute__((address_space(1))) const unsigned int*)(const void*)g,
      (__attribute__((address_space(3))) unsigned int*)(void*)l,
      16, 0, 0);
}

// ---------------- K/V projection, parallelism-first (v11) ----------------
// r6's W-stationary version: 256 blocks = 1 wave/SIMD, serial 6-shfl chain
// per iteration -> 84 us of exposed latency (VGPR=16, 0.4% HBM). Rewrite:
// 2048 blocks (isV x b x l x 8 f-groups) = 8 blocks/CU = 32 waves/CU (full).
// Thread = (f-row, e-quarter): 32 independent float4-pair loads (unroll 8),
// 2 shfl_xor to combine the quad. src row (2KB) L1-broadcast per block.
// W re-read = 256 MB L2 = ~7.5 us floor; latency now hidden by TLP.
__global__ __launch_bounds__(256) void kvproj_kernel(
    const float* __restrict__ key, const float* __restrict__ val,
    const float* __restrict__ Wk, const float* __restrict__ bk,
    const float* __restrict__ Wv, const float* __restrict__ bv,
    float* __restrict__ kproj, float* __restrict__ vproj) {
  const int blk = blockIdx.x;
  const bool isV = blk & 1;
  const int b = (blk >> 1) & 7;
  const int l = (blk >> 4) & 15;
  const int fg = blk >> 8;               // [0,8)
  const int tid = threadIdx.x;
  const int fl = tid >> 2, es = tid & 3;
  const int f = fg * 64 + fl;
  const float4* s4 = (const float4*)((isV ? val : key) + ((size_t)l * NBATCH + b) * EMBED + es * 128);
  const float4* w4 = (const float4*)((isV ? Wv : Wk) + (size_t)f * EMBED + es * 128);
  float acc = 0.f;
#pragma unroll 8
  for (int i = 0; i < 32; i++) {
    float4 a = s4[i], w = w4[i];
    acc += a.x * w.x + a.y * w.y + a.z * w.z + a.w * w.w;
  }
  acc += __shfl_xor(acc, 1);
  acc += __shfl_xor(acc, 2);
  if (es == 0) {
    acc += (isV ? bv : bk)[f];
    if (!isV) {
      kproj[((size_t)(b * EMBED + f)) * NCLS + l] = acc;           // [b][h][d][l]
    } else {
      int h = f >> 6, d = f & 63;
      vproj[(size_t)b * 8192 + (size_t)h * 1024 + l * 64 + d] = acc;  // [b][h][l][d]
    }
  }
}

// ---------------- merged build: Kq / WoV / sb (r6, passing) ----------------
__global__ __launch_bounds__(256) void build_all(
    const float* __restrict__ kproj, const float* __restrict__ vproj,
    const float* __restrict__ Wq, const float* __restrict__ bq,
    const float* __restrict__ Wo,
    u16* __restrict__ Kqb, u16* __restrict__ WoVb, float* __restrict__ sb) {
  const int blk = blockIdx.x;
  if (blk < 2048) {
    int t = blk * 256 + threadIdx.x;   // 8*128*512
    int e = t & 511;
    int hl = (t >> 9) & 127;
    int b = t >> 16;
    int h = hl >> 4, l = hl & 15;
    const float* kp = kproj + (size_t)b * 8192 + h * 1024 + l;
    const float* wq = Wq + (size_t)(h * 64) * 512 + e;
    float acc = 0.f;
#pragma unroll 16
    for (int d = 0; d < 64; d++) acc += kp[d * 16] * wq[d * 512];
    Kqb[t] = f2bf(acc);
  } else if (blk < 3072) {
    const int wave = threadIdx.x >> 6;
    const int lane = threadIdx.x & 63;
    const int wgid = (blk - 2048) * 4 + wave;   // [0,4096)
    const int b = wgid >> 9, f = wgid & 511;
    const int l = lane >> 2, c = lane & 3;
    const float* vp = vproj + (size_t)b * 8192 + l * 64 + c * 16;
    const float* wo = Wo + (size_t)f * 512 + c * 16;
#pragma unroll 2
    for (int h = 0; h < 8; h++) {
      const float* v = vp + h * 1024;
      const float* w = wo + h * 64;
      float4 v0 = *(const float4*)v,       w0 = *(const float4*)w;
      float4 v1 = *(const float4*)(v + 4), w1 = *(const float4*)(w + 4);
      float4 v2 = *(const float4*)(v + 8), w2 = *(const float4*)(w + 8);
      float4 v3 = *(const float4*)(v + 12), w3 = *(const float4*)(w + 12);
      float acc = v0.x * w0.x + v0.y * w0.y + v0.z * w0.z + v0.w * w0.w +
                  v1.x * w1.x + v1.y * w1.y + v1.z * w1.z + v1.w * w1.w +
                  v2.x * w2.x + v2.y * w2.y + v2.z * w2.z + v2.w * w2.w +
                  v3.x * w3.x + v3.y * w3.y + v3.z * w3.z + v3.w * w3.w;
      acc += __shfl_xor(acc, 1);
      acc += __shfl_xor(acc, 2);
      if (c == 0) WoVb[(size_t)b * 65536 + (size_t)f * 128 + h * 16 + l] = f2bf(acc);
    }
  } else {
    int t = (blk - 3072) * 256 + threadIdx.x;   // 1024
    int hl = t & 127, b = t >> 7;
    int h = hl >> 4, l = hl & 15;
    const float* kp = kproj + (size_t)b * 8192 + h * 1024 + l;
    const float* q = bq + h * 64;
    float acc = 0.f;
#pragma unroll
    for (int d = 0; d < 64; d++) acc += q[d] * kp[d * 16];
    sb[t] = acc;
  }
}

// ---------------- fused: scores GEMM + softmax + out GEMM (r10, passing) ----------------
// v10: slot in HIGH bit (XCD parity fix). Byte-identical to r10.
__global__ __launch_bounds__(256) void fused_attn(
    const float* __restrict__ query, const u16* __restrict__ Kqb,
    const u16* __restrict__ WoVb, const float* __restrict__ sb,
    const float* __restrict__ bo, const int* __restrict__ bidx,
    float* __restrict__ out) {
  __shared__ __align__(16) u16 Bs[2][128 * 64];   // 32 KB: Kq k-slice, dbuf
  __shared__ __align__(16) u16 Ps[64 * 128];      // 16 KB: P, XOR-swizzled
  const int tid = threadIdx.x;
  const int lane = tid & 63;
  const int wave = tid >> 6;
  const int quad = lane >> 4;
  const int l16 = lane & 15;
  const int tileId = blockIdx.x & 511;    // slot in HIGH bit (XCD parity fix)
  const int slot = blockIdx.x >> 9;
  const int m0 = tileId * 64;
  const int bFirst = bidx[m0];
  const int bLast = bidx[m0 + 63];
  if (slot == 1 && bFirst == bLast) return;   // uniform exit, before any barrier
  const int b0 = (slot == 0) ? bFirst : bFirst + 1;
  const int b1 = (slot == 0) ? bFirst : bLast;

  // staging coords (BK=64): 1024 chunks of 16B per 16KB slice; thread owns
  // chunks c_i = tid + i*256 (i=0..3). c -> row=c>>3, physchunk=c&7.
  const int rB = tid >> 3;                       // row of chunk 0
  const int lgB = (tid & 7) ^ (rB & 7);          // global chunk for phys (tid&7)
  const size_t bbase = (size_t)rB * 512 + lgB * 8;   // u16 elems; +i*32*512

  // per-row batch for predicated stores (phase 2: wave covers all 64 rows)
  int rowb[4][4];
#pragma unroll
  for (int mi = 0; mi < 4; mi++)
#pragma unroll
    for (int r = 0; r < 4; r++) rowb[mi][r] = bidx[m0 + mi * 16 + quad * 4 + r];

  // phase-1 A pointer: wave-exclusive row (fp32), quad picks 8-elem sub-slice
  const float* pA = query + (size_t)(m0 + wave * 16 + l16) * 512 + quad * 8;

  for (int bb = b0; bb <= b1; bb++) {
    const u16* Bq = Kqb + (size_t)bb * 65536;

    // prologue: stage k-slice 0 into buf 0; load A slice 0 (fp32)
#pragma unroll
    for (int i = 0; i < 4; i++)
      async16(Bq + bbase + (size_t)i * 32 * 512, &Bs[0][(tid + i * 256) * 8]);
    float4 aC[4];
    aC[0] = *(const float4*)(pA);
    aC[1] = *(const float4*)(pA + 4);
    aC[2] = *(const float4*)(pA + 32);
    aC[3] = *(const float4*)(pA + 36);

    f32x4 acc1[8];
#pragma unroll
    for (int j = 0; j < 8; j++) acc1[j] = (f32x4){0.f, 0.f, 0.f, 0.f};

    for (int t = 0; t < 8; t++) {
      __syncthreads();                     // drains vmcnt -> buf[t&1] + A(t) ready
      const int cur = t & 1;
      if (t < 7) {                         // stage next k-slice; overlaps MFMA below
        const size_t ko = (size_t)(t + 1) * 64;
#pragma unroll
        for (int i = 0; i < 4; i++)
          async16(Bq + bbase + ko + (size_t)i * 32 * 512, &Bs[cur ^ 1][(tid + i * 256) * 8]);
      }
      float4 a0 = aC[0], a1 = aC[1], a2 = aC[2], a3 = aC[3];
      if (t < 7) {                         // prefetch A(t+1)
        const float* p = pA + (t + 1) * 64;
        aC[0] = *(const float4*)(p);
        aC[1] = *(const float4*)(p + 4);
        aC[2] = *(const float4*)(p + 32);
        aC[3] = *(const float4*)(p + 36);
      }
      short8 af[2];
      af[0][0] = (short)f2bf(a0.x); af[0][1] = (short)f2bf(a0.y);
      af[0][2] = (short)f2bf(a0.z); af[0][3] = (short)f2bf(a0.w);
      af[0][4] = (short)f2bf(a1.x); af[0][5] = (short)f2bf(a1.y);
      af[0][6] = (short)f2bf(a1.z); af[0][7] = (short)f2bf(a1.w);
      af[1][0] = (short)f2bf(a2.x); af[1][1] = (short)f2bf(a2.y);
      af[1][2] = (short)f2bf(a2.z); af[1][3] = (short)f2bf(a2.w);
      af[1][4] = (short)f2bf(a3.x); af[1][5] = (short)f2bf(a3.y);
      af[1][6] = (short)f2bf(a3.z); af[1][7] = (short)f2bf(a3.w);
      __builtin_amdgcn_s_setprio(1);
#pragma unroll
      for (int kk = 0; kk < 2; kk++) {
#pragma unroll
        for (int ni = 0; ni < 8; ni++) {
          const int rw = ni * 16 + l16;
          const int phys = (kk * 4 + quad) ^ (rw & 7);
          short8 bfr = *(const short8*)&Bs[cur][rw * 64 + phys * 8];
          acc1[ni] = __builtin_amdgcn_mfma_f32_16x16x32_bf16(af[kk], bfr, acc1[ni], 0, 0, 0);
        }
      }
      __builtin_amdgcn_s_setprio(0);
    }

    // ---- softmax over each head's 16 l-cols (16-lane shfl), P -> LDS ----
    float sbv[8];
#pragma unroll
    for (int ni = 0; ni < 8; ni++) sbv[ni] = sb[bb * 128 + ni * 16 + l16];
#pragma unroll
    for (int r = 0; r < 4; r++) {
      const int row = wave * 16 + quad * 4 + r;   // wave-exclusive rows
#pragma unroll
      for (int ni = 0; ni < 8; ni++) {
        float v = acc1[ni][r] + sbv[ni];
        float mx = v;
        mx = fmaxf(mx, __shfl_xor(mx, 1));
        mx = fmaxf(mx, __shfl_xor(mx, 2));
        mx = fmaxf(mx, __shfl_xor(mx, 4));
        mx = fmaxf(mx, __shfl_xor(mx, 8));
        float ev = __expf((v - mx) * 0.125f);   // scale = D^-0.5
        float s = ev;
        s += __shfl_xor(s, 1);
        s += __shfl_xor(s, 2);
        s += __shfl_xor(s, 4);
        s += __shfl_xor(s, 8);
        const int col = ni * 16 + l16;
        Ps[row * 128 + (((col >> 3) ^ (row & 7)) << 3) + (col & 7)] = f2bf(ev / s);
      }
    }
    __syncthreads();   // all P stripes visible

    // ---- phase 2: out[64,512] = P x WoV[bb]^T; wave owns 128 f-cols ----
    const u16* Wv = WoVb + (size_t)bb * 65536;
#pragma unroll
    for (int h2 = 0; h2 < 2; h2++) {
      const int f0 = wave * 128 + h2 * 64;
      f32x4 acc2[4][4];
#pragma unroll
      for (int i = 0; i < 4; i++)
#pragma unroll
        for (int j = 0; j < 4; j++) acc2[i][j] = (f32x4){0.f, 0.f, 0.f, 0.f};
#pragma unroll
      for (int kk = 0; kk < 4; kk++) {
        short8 paf[4], bf2[4];
#pragma unroll
        for (int mi = 0; mi < 4; mi++) {
          const int row = mi * 16 + l16;
          paf[mi] = *(const short8*)&Ps[row * 128 + (((kk * 4 + quad) ^ (row & 7)) << 3)];
        }
#pragma unroll
        for (int ni = 0; ni < 4; ni++) {
          const int fr = f0 + ni * 16 + l16;
          bf2[ni] = *(const short8*)(Wv + (size_t)fr * 128 + kk * 32 + quad * 8);
        }
        __builtin_amdgcn_s_setprio(1);
#pragma unroll
        for (int mi = 0; mi < 4; mi++)
#pragma unroll
          for (int ni = 0; ni < 4; ni++)
            acc2[mi][ni] = __builtin_amdgcn_mfma_f32_16x16x32_bf16(paf[mi], bf2[ni], acc2[mi][ni], 0, 0, 0);
        __builtin_amdgcn_s_setprio(0);
      }
      float bov[4];
#pragma unroll
      for (int ni = 0; ni < 4; ni++) bov[ni] = bo[f0 + ni * 16 + l16];
#pragma unroll
      for (int mi = 0; mi < 4; mi++)
#pragma unroll
        for (int r = 0; r < 4; r++) {
          if (rowb[mi][r] == bb) {
            const size_t row = m0 + mi * 16 + quad * 4 + r;
#pragma unroll
            for (int ni = 0; ni < 4; ni++)
              out[row * 512 + f0 + ni * 16 + l16] = acc2[mi][ni][r] + bov[ni];
          }
        }
    }
    __syncthreads();   // Ps/Bs safe to overwrite next bb
  }
}

extern "C" void kernel_launch(void* const* d_in, const int* in_sizes, int n_in,
                              void* d_out, int out_size, void* d_ws, size_t ws_size,
                              hipStream_t stream) {
  const float* query = (const float*)d_in[0];
  const float* keyt = (const float*)d_in[1];
  const float* valt = (const float*)d_in[2];
  const int* bidx = (const int*)d_in[3];
  // d_in[4] = batch_size (scalar, fixed = 8)
  const float* Wq = (const float*)d_in[5];
  const float* bq = (const float*)d_in[6];
  const float* Wk = (const float*)d_in[7];
  const float* bk = (const float*)d_in[8];
  const float* Wv = (const float*)d_in[9];
  const float* bv = (const float*)d_in[10];
  const float* Wo = (const float*)d_in[11];
  const float* bo = (const float*)d_in[12];
  float* out = (float*)d_out;

  // workspace layout (bytes)
  unsigned char* w = (unsigned char*)d_ws;
  float* kproj = (float*)(w + 41943040ull);   //    262,144: [B,H,D,L]
  float* vproj = (float*)(w + 42205184ull);   //    262,144: [B,H,L,D]
  u16* Kqb = (u16*)(w + 42467328ull);         //  1,048,576: [B,128,512] bf16
  u16* WoVb = (u16*)(w + 43515904ull);        //  1,048,576: [B,512,128] bf16
  float* sb = (float*)(w + 44564480ull);      //      4,096: [B,128]

  // 1) K/V projections (fp32, parallelism-first: 2048 blocks, 32 waves/CU)
  kvproj_kernel<<<2048, 256, 0, stream>>>(keyt, valt, Wk, bk, Wv, bv, kproj, vproj);

  // 2) fold Wq through k, Wo through v, and sb — one launch
  build_all<<<3076, 256, 0, stream>>>(kproj, vproj, Wq, bq, Wo, Kqb, WoVb, sb);

  // 3) fused: fp32 query -> scores -> softmax -> out (slot in HIGH bit)
  fused_attn<<<N_TOKENS / 64 * 2, 256, 0, stream>>>(query, Kqb, WoVb, sb, bo, bidx, out);
}

// Round 12
// 252.563 us; speedup vs baseline: 1.2784x; 1.0521x over previous
//
#include <hip/hip_runtime.h>

typedef unsigned short u16;
typedef __attribute__((ext_vector_type(8))) short short8;
typedef __attribute__((ext_vector_type(4))) unsigned short u16x4;
typedef __attribute__((ext_vector_type(4))) float f32x4;

#define N_TOKENS 32768
#define EMBED 512
#define NCLS 16
#define NBATCH 8
#define NHEAD 8
#define DHEAD 64

__device__ __forceinline__ u16 f2bf(float f) {
  unsigned u = __float_as_uint(f);
  u += 0x7fffu + ((u >> 16) & 1u);   // RNE
  return (u16)(u >> 16);
}

__device__ __forceinline__ void async16(const u16* g, u16* l) {
  __builtin_amdgcn_global_load_lds(
      (__attribute__((address_space(1))) const unsigned int*)(const void*)g,
      (__attribute__((address_space(3))) unsigned int*)(void*)l,
      16, 0, 0);
}

// ---------------- K/V projection v12: coalesced wave-per-row ----------------
// r10 version: latency-bound (1 wave/SIMD, serial 6x ~120cyc shfl chain).
// r11 version: request-bound (lanes 512B apart -> 64 cache lines PER LOAD).
// v12 fixes both: wave-per-f-row -> lane i reads W[f, i*8..] = two fully
// coalesced 2KB transactions per row; 16 rows/wave in 4-row ILP groups
// (group g+1's 8 loads overlap group g's shfl chains); 2048 blocks = 8/CU.
// W traffic 256MB L2 coalesced = ~8us floor; x row L1-hot.
__global__ __launch_bounds__(256) void kvproj_kernel(
    const float* __restrict__ key, const float* __restrict__ val,
    const float* __restrict__ Wk, const float* __restrict__ bk,
    const float* __restrict__ Wv, const float* __restrict__ bv,
    float* __restrict__ kproj, float* __restrict__ vproj) {
  const int blk = blockIdx.x;           // isV(1) | b(3) | l(4) | fg(3)
  const bool isV = blk & 1;
  const int b = (blk >> 1) & 7;
  const int l = (blk >> 4) & 15;
  const int fg = blk >> 8;              // [0,8)
  const int wave = threadIdx.x >> 6;
  const int lane = threadIdx.x & 63;
  const int fbase = fg * 64 + wave * 16;   // wave owns 16 f-rows
  const float* x = (isV ? val : key) + ((size_t)l * NBATCH + b) * EMBED;
  const float* W = isV ? Wv : Wk;
  const float* bias = isV ? bv : bk;

  float4 x0 = *(const float4*)(x + lane * 8);
  float4 x1 = *(const float4*)(x + lane * 8 + 4);

#pragma unroll
  for (int grp = 0; grp < 4; grp++) {
    float acc[4];
#pragma unroll
    for (int j = 0; j < 4; j++) {
      const float* w = W + (size_t)(fbase + grp * 4 + j) * EMBED + lane * 8;
      float4 w0 = *(const float4*)w;
      float4 w1 = *(const float4*)(w + 4);
      acc[j] = x0.x * w0.x + x0.y * w0.y + x0.z * w0.z + x0.w * w0.w +
               x1.x * w1.x + x1.y * w1.y + x1.z * w1.z + x1.w * w1.w;
    }
#pragma unroll
    for (int j = 0; j < 4; j++) {
      acc[j] += __shfl_xor(acc[j], 1);
      acc[j] += __shfl_xor(acc[j], 2);
      acc[j] += __shfl_xor(acc[j], 4);
      acc[j] += __shfl_xor(acc[j], 8);
      acc[j] += __shfl_xor(acc[j], 16);
      acc[j] += __shfl_xor(acc[j], 32);
    }
#pragma unroll
    for (int j = 0; j < 4; j++) {
      if (lane == j) {                   // compile-time acc index (no scratch)
        const int f = fbase + grp * 4 + j;
        float v = acc[j] + bias[f];
        if (!isV) {
          kproj[((size_t)(b * EMBED + f)) * NCLS + l] = v;            // [b][h][d][l]
        } else {
          vproj[(size_t)b * 8192 + (size_t)(f >> 6) * 1024 + l * 64 + (f & 63)] = v;
        }
      }
    }
  }
}

// ---------------- merged build: Kq / WoV / sb (r6, passing) ----------------
__global__ __launch_bounds__(256) void build_all(
    const float* __restrict__ kproj, const float* __restrict__ vproj,
    const float* __restrict__ Wq, const float* __restrict__ bq,
    const float* __restrict__ Wo,
    u16* __restrict__ Kqb, u16* __restrict__ WoVb, float* __restrict__ sb) {
  const int blk = blockIdx.x;
  if (blk < 2048) {
    int t = blk * 256 + threadIdx.x;   // 8*128*512
    int e = t & 511;
    int hl = (t >> 9) & 127;
    int b = t >> 16;
    int h = hl >> 4, l = hl & 15;
    const float* kp = kproj + (size_t)b * 8192 + h * 1024 + l;
    const float* wq = Wq + (size_t)(h * 64) * 512 + e;
    float acc = 0.f;
#pragma unroll 16
    for (int d = 0; d < 64; d++) acc += kp[d * 16] * wq[d * 512];
    Kqb[t] = f2bf(acc);
  } else if (blk < 3072) {
    const int wave = threadIdx.x >> 6;
    const int lane = threadIdx.x & 63;
    const int wgid = (blk - 2048) * 4 + wave;   // [0,4096)
    const int b = wgid >> 9, f = wgid & 511;
    const int l = lane >> 2, c = lane & 3;
    const float* vp = vproj + (size_t)b * 8192 + l * 64 + c * 16;
    const float* wo = Wo + (size_t)f * 512 + c * 16;
#pragma unroll 2
    for (int h = 0; h < 8; h++) {
      const float* v = vp + h * 1024;
      const float* w = wo + h * 64;
      float4 v0 = *(const float4*)v,       w0 = *(const float4*)w;
      float4 v1 = *(const float4*)(v + 4), w1 = *(const float4*)(w + 4);
      float4 v2 = *(const float4*)(v + 8), w2 = *(const float4*)(w + 8);
      float4 v3 = *(const float4*)(v + 12), w3 = *(const float4*)(w + 12);
      float acc = v0.x * w0.x + v0.y * w0.y + v0.z * w0.z + v0.w * w0.w +
                  v1.x * w1.x + v1.y * w1.y + v1.z * w1.z + v1.w * w1.w +
                  v2.x * w2.x + v2.y * w2.y + v2.z * w2.z + v2.w * w2.w +
                  v3.x * w3.x + v3.y * w3.y + v3.z * w3.z + v3.w * w3.w;
      acc += __shfl_xor(acc, 1);
      acc += __shfl_xor(acc, 2);
      if (c == 0) WoVb[(size_t)b * 65536 + (size_t)f * 128 + h * 16 + l] = f2bf(acc);
    }
  } else {
    int t = (blk - 3072) * 256 + threadIdx.x;   // 1024
    int hl = t & 127, b = t >> 7;
    int h = hl >> 4, l = hl & 15;
    const float* kp = kproj + (size_t)b * 8192 + h * 1024 + l;
    const float* q = bq + h * 64;
    float acc = 0.f;
#pragma unroll
    for (int d = 0; d < 64; d++) acc += q[d] * kp[d * 16];
    sb[t] = acc;
  }
}

// ---------------- fused: scores GEMM + softmax + out GEMM ----------------
// v12 = r10 body + __launch_bounds__(256,3): natural VGPR was 172, two regs
// above the 3-blocks/CU threshold (512/3=170). Minimal cap -> +50% residency.
// WRITE_SIZE canary: must stay exactly 65536 KB (any growth = spills, revert).
__global__ __launch_bounds__(256, 3) void fused_attn(
    const float* __restrict__ query, const u16* __restrict__ Kqb,
    const u16* __restrict__ WoVb, const float* __restrict__ sb,
    const float* __restrict__ bo, const int* __restrict__ bidx,
    float* __restrict__ out) {
  __shared__ __align__(16) u16 Bs[2][128 * 64];   // 32 KB: Kq k-slice, dbuf
  __shared__ __align__(16) u16 Ps[64 * 128];      // 16 KB: P, XOR-swizzled
  const int tid = threadIdx.x;
  const int lane = tid & 63;
  const int wave = tid >> 6;
  const int quad = lane >> 4;
  const int l16 = lane & 15;
  const int tileId = blockIdx.x & 511;    // slot in HIGH bit (XCD parity fix)
  const int slot = blockIdx.x >> 9;
  const int m0 = tileId * 64;
  const int bFirst = bidx[m0];
  const int bLast = bidx[m0 + 63];
  if (slot == 1 && bFirst == bLast) return;   // uniform exit, before any barrier
  const int b0 = (slot == 0) ? bFirst : bFirst + 1;
  const int b1 = (slot == 0) ? bFirst : bLast;

  // staging coords (BK=64): 1024 chunks of 16B per 16KB slice; thread owns
  // chunks c_i = tid + i*256 (i=0..3). c -> row=c>>3, physchunk=c&7.
  const int rB = tid >> 3;                       // row of chunk 0
  const int lgB = (tid & 7) ^ (rB & 7);          // global chunk for phys (tid&7)
  const size_t bbase = (size_t)rB * 512 + lgB * 8;   // u16 elems; +i*32*512

  // per-row batch for predicated stores (phase 2: wave covers all 64 rows)
  int rowb[4][4];
#pragma unroll
  for (int mi = 0; mi < 4; mi++)
#pragma unroll
    for (int r = 0; r < 4; r++) rowb[mi][r] = bidx[m0 + mi * 16 + quad * 4 + r];

  // phase-1 A pointer: wave-exclusive row (fp32), quad picks 8-elem sub-slice
  const float* pA = query + (size_t)(m0 + wave * 16 + l16) * 512 + quad * 8;

  for (int bb = b0; bb <= b1; bb++) {
    const u16* Bq = Kqb + (size_t)bb * 65536;

    // prologue: stage k-slice 0 into buf 0; load A slice 0 (fp32)
#pragma unroll
    for (int i = 0; i < 4; i++)
      async16(Bq + bbase + (size_t)i * 32 * 512, &Bs[0][(tid + i * 256) * 8]);
    float4 aC[4];
    aC[0] = *(const float4*)(pA);
    aC[1] = *(const float4*)(pA + 4);
    aC[2] = *(const float4*)(pA + 32);
    aC[3] = *(const float4*)(pA + 36);

    f32x4 acc1[8];
#pragma unroll
    for (int j = 0; j < 8; j++) acc1[j] = (f32x4){0.f, 0.f, 0.f, 0.f};

    for (int t = 0; t < 8; t++) {
      __syncthreads();                     // drains vmcnt -> buf[t&1] + A(t) ready
      const int cur = t & 1;
      if (t < 7) {                         // stage next k-slice; overlaps MFMA below
        const size_t ko = (size_t)(t + 1) * 64;
#pragma unroll
        for (int i = 0; i < 4; i++)
          async16(Bq + bbase + ko + (size_t)i * 32 * 512, &Bs[cur ^ 1][(tid + i * 256) * 8]);
      }
      float4 a0 = aC[0], a1 = aC[1], a2 = aC[2], a3 = aC[3];
      if (t < 7) {                         // prefetch A(t+1)
        const float* p = pA + (t + 1) * 64;
        aC[0] = *(const float4*)(p);
        aC[1] = *(const float4*)(p + 4);
        aC[2] = *(const float4*)(p + 32);
        aC[3] = *(const float4*)(p + 36);
      }
      short8 af[2];
      af[0][0] = (short)f2bf(a0.x); af[0][1] = (short)f2bf(a0.y);
      af[0][2] = (short)f2bf(a0.z); af[0][3] = (short)f2bf(a0.w);
      af[0][4] = (short)f2bf(a1.x); af[0][5] = (short)f2bf(a1.y);
      af[0][6] = (short)f2bf(a1.z); af[0][7] = (short)f2bf(a1.w);
      af[1][0] = (short)f2bf(a2.x); af[1][1] = (short)f2bf(a2.y);
      af[1][2] = (short)f2bf(a2.z); af[1][3] = (short)f2bf(a2.w);
      af[1][4] = (short)f2bf(a3.x); af[1][5] = (short)f2bf(a3.y);
      af[1][6] = (short)f2bf(a3.z); af[1][7] = (short)f2bf(a3.w);
      __builtin_amdgcn_s_setprio(1);
#pragma unroll
      for (int kk = 0; kk < 2; kk++) {
#pragma unroll
        for (int ni = 0; ni < 8; ni++) {
          const int rw = ni * 16 + l16;
          const int phys = (kk * 4 + quad) ^ (rw & 7);
          short8 bfr = *(const short8*)&Bs[cur][rw * 64 + phys * 8];
          acc1[ni] = __builtin_amdgcn_mfma_f32_16x16x32_bf16(af[kk], bfr, acc1[ni], 0, 0, 0);
        }
      }
      __builtin_amdgcn_s_setprio(0);
    }

    // ---- softmax over each head's 16 l-cols (16-lane shfl), P -> LDS ----
    float sbv[8];
#pragma unroll
    for (int ni = 0; ni < 8; ni++) sbv[ni] = sb[bb * 128 + ni * 16 + l16];
#pragma unroll
    for (int r = 0; r < 4; r++) {
      const int row = wave * 16 + quad * 4 + r;   // wave-exclusive rows
#pragma unroll
      for (int ni = 0; ni < 8; ni++) {
        float v = acc1[ni][r] + sbv[ni];
        float mx = v;
        mx = fmaxf(mx, __shfl_xor(mx, 1));
        mx = fmaxf(mx, __shfl_xor(mx, 2));
        mx = fmaxf(mx, __shfl_xor(mx, 4));
        mx = fmaxf(mx, __shfl_xor(mx, 8));
        float ev = __expf((v - mx) * 0.125f);   // scale = D^-0.5
        float s = ev;
        s += __shfl_xor(s, 1);
        s += __shfl_xor(s, 2);
        s += __shfl_xor(s, 4);
        s += __shfl_xor(s, 8);
        const int col = ni * 16 + l16;
        Ps[row * 128 + (((col >> 3) ^ (row & 7)) << 3) + (col & 7)] = f2bf(ev / s);
      }
    }
    __syncthreads();   // all P stripes visible

    // ---- phase 2: out[64,512] = P x WoV[bb]^T; wave owns 128 f-cols ----
    const u16* Wv = WoVb + (size_t)bb * 65536;
#pragma unroll
    for (int h2 = 0; h2 < 2; h2++) {
      const int f0 = wave * 128 + h2 * 64;
      f32x4 acc2[4][4];
#pragma unroll
      for (int i = 0; i < 4; i++)
#pragma unroll
        for (int j = 0; j < 4; j++) acc2[i][j] = (f32x4){0.f, 0.f, 0.f, 0.f};
#pragma unroll
      for (int kk = 0; kk < 4; kk++) {
        short8 paf[4], bf2[4];
#pragma unroll
        for (int mi = 0; mi < 4; mi++) {
          const int row = mi * 16 + l16;
          paf[mi] = *(const short8*)&Ps[row * 128 + (((kk * 4 + quad) ^ (row & 7)) << 3)];
        }
#pragma unroll
        for (int ni = 0; ni < 4; ni++) {
          const int fr = f0 + ni * 16 + l16;
          bf2[ni] = *(const short8*)(Wv + (size_t)fr * 128 + kk * 32 + quad * 8);
        }
        __builtin_amdgcn_s_setprio(1);
#pragma unroll
        for (int mi = 0; mi < 4; mi++)
#pragma unroll
          for (int ni = 0; ni < 4; ni++)
            acc2[mi][ni] = __builtin_amdgcn_mfma_f32_16x16x32_bf16(paf[mi], bf2[ni], acc2[mi][ni], 0, 0, 0);
        __builtin_amdgcn_s_setprio(0);
      }
      float bov[4];
#pragma unroll
      for (int ni = 0; ni < 4; ni++) bov[ni] = bo[f0 + ni * 16 + l16];
#pragma unroll
      for (int mi = 0; mi < 4; mi++)
#pragma unroll
        for (int r = 0; r < 4; r++) {
          if (rowb[mi][r] == bb) {
            const size_t row = m0 + mi * 16 + quad * 4 + r;
#pragma unroll
            for (int ni = 0; ni < 4; ni++)
              out[row * 512 + f0 + ni * 16 + l16] = acc2[mi][ni][r] + bov[ni];
          }
        }
    }
    __syncthreads();   // Ps/Bs safe to overwrite next bb
  }
}

extern "C" void kernel_launch(void* const* d_in, const int* in_sizes, int n_in,
                              void* d_out, int out_size, void* d_ws, size_t ws_size,
                              hipStream_t stream) {
  const float* query = (const float*)d_in[0];
  const float* keyt = (const float*)d_in[1];
  const float* valt = (const float*)d_in[2];
  const int* bidx = (const int*)d_in[3];
  // d_in[4] = batch_size (scalar, fixed = 8)
  const float* Wq = (const float*)d_in[5];
  const float* bq = (const float*)d_in[6];
  const float* Wk = (const float*)d_in[7];
  const float* bk = (const float*)d_in[8];
  const float* Wv = (const float*)d_in[9];
  const float* bv = (const float*)d_in[10];
  const float* Wo = (const float*)d_in[11];
  const float* bo = (const float*)d_in[12];
  float* out = (float*)d_out;

  // workspace layout (bytes)
  unsigned char* w = (unsigned char*)d_ws;
  float* kproj = (float*)(w + 41943040ull);   //    262,144: [B,H,D,L]
  float* vproj = (float*)(w + 42205184ull);   //    262,144: [B,H,L,D]
  u16* Kqb = (u16*)(w + 42467328ull);         //  1,048,576: [B,128,512] bf16
  u16* WoVb = (u16*)(w + 43515904ull);        //  1,048,576: [B,512,128] bf16
  float* sb = (float*)(w + 44564480ull);      //      4,096: [B,128]

  // 1) K/V projections (coalesced wave-per-row, 2048 blocks)
  kvproj_kernel<<<2048, 256, 0, stream>>>(keyt, valt, Wk, bk, Wv, bv, kproj, vproj);

  // 2) fold Wq through k, Wo through v, and sb — one launch
  build_all<<<3076, 256, 0, stream>>>(kproj, vproj, Wq, bq, Wo, Kqb, WoVb, sb);

  // 3) fused: fp32 query -> scores -> softmax -> out (slot in HIGH bit)
  fused_attn<<<N_TOKENS / 64 * 2, 256, 0, stream>>>(query, Kqb, WoVb, sb, bo, bidx, out);
}

// Round 13
// 223.620 us; speedup vs baseline: 1.4438x; 1.1294x over previous
//
#include <hip/hip_runtime.h>

typedef unsigned short u16;
typedef __attribute__((ext_vector_type(8))) short short8;
typedef __attribute__((ext_vector_type(4))) unsigned short u16x4;
typedef __attribute__((ext_vector_type(4))) float f32x4;

#define N_TOKENS 32768
#define EMBED 512
#define NCLS 16
#define NBATCH 8
#define NHEAD 8
#define DHEAD 64

__device__ __forceinline__ u16 f2bf(float f) {
  unsigned u = __float_as_uint(f);
  u += 0x7fffu + ((u >> 16) & 1u);   // RNE
  return (u16)(u >> 16);
}

__device__ __forceinline__ void async16(const u16* g, u16* l) {
  __builtin_amdgcn_global_load_lds(
      (__attribute__((address_space(1))) const unsigned int*)(const void*)g,
      (__attribute__((address_space(3))) unsigned int*)(void*)l,
      16, 0, 0);
}

// ---------------- K/V projection v12: coalesced wave-per-row (r12, fast) ----------------
__global__ __launch_bounds__(256) void kvproj_kernel(
    const float* __restrict__ key, const float* __restrict__ val,
    const float* __restrict__ Wk, const float* __restrict__ bk,
    const float* __restrict__ Wv, const float* __restrict__ bv,
    float* __restrict__ kproj, float* __restrict__ vproj) {
  const int blk = blockIdx.x;           // isV(1) | b(3) | l(4) | fg(3)
  const bool isV = blk & 1;
  const int b = (blk >> 1) & 7;
  const int l = (blk >> 4) & 15;
  const int fg = blk >> 8;              // [0,8)
  const int wave = threadIdx.x >> 6;
  const int lane = threadIdx.x & 63;
  const int fbase = fg * 64 + wave * 16;   // wave owns 16 f-rows
  const float* x = (isV ? val : key) + ((size_t)l * NBATCH + b) * EMBED;
  const float* W = isV ? Wv : Wk;
  const float* bias = isV ? bv : bk;

  float4 x0 = *(const float4*)(x + lane * 8);
  float4 x1 = *(const float4*)(x + lane * 8 + 4);

#pragma unroll
  for (int grp = 0; grp < 4; grp++) {
    float acc[4];
#pragma unroll
    for (int j = 0; j < 4; j++) {
      const float* w = W + (size_t)(fbase + grp * 4 + j) * EMBED + lane * 8;
      float4 w0 = *(const float4*)w;
      float4 w1 = *(const float4*)(w + 4);
      acc[j] = x0.x * w0.x + x0.y * w0.y + x0.z * w0.z + x0.w * w0.w +
               x1.x * w1.x + x1.y * w1.y + x1.z * w1.z + x1.w * w1.w;
    }
#pragma unroll
    for (int j = 0; j < 4; j++) {
      acc[j] += __shfl_xor(acc[j], 1);
      acc[j] += __shfl_xor(acc[j], 2);
      acc[j] += __shfl_xor(acc[j], 4);
      acc[j] += __shfl_xor(acc[j], 8);
      acc[j] += __shfl_xor(acc[j], 16);
      acc[j] += __shfl_xor(acc[j], 32);
    }
#pragma unroll
    for (int j = 0; j < 4; j++) {
      if (lane == j) {                   // compile-time acc index (no scratch)
        const int f = fbase + grp * 4 + j;
        float v = acc[j] + bias[f];
        if (!isV) {
          kproj[((size_t)(b * EMBED + f)) * NCLS + l] = v;            // [b][h][d][l]
        } else {
          vproj[(size_t)b * 8192 + (size_t)(f >> 6) * 1024 + l * 64 + (f & 63)] = v;
        }
      }
    }
  }
}

// ---------------- merged build: Kq / WoV / sb (r6, passing) ----------------
__global__ __launch_bounds__(256) void build_all(
    const float* __restrict__ kproj, const float* __restrict__ vproj,
    const float* __restrict__ Wq, const float* __restrict__ bq,
    const float* __restrict__ Wo,
    u16* __restrict__ Kqb, u16* __restrict__ WoVb, float* __restrict__ sb) {
  const int blk = blockIdx.x;
  if (blk < 2048) {
    int t = blk * 256 + threadIdx.x;   // 8*128*512
    int e = t & 511;
    int hl = (t >> 9) & 127;
    int b = t >> 16;
    int h = hl >> 4, l = hl & 15;
    const float* kp = kproj + (size_t)b * 8192 + h * 1024 + l;
    const float* wq = Wq + (size_t)(h * 64) * 512 + e;
    float acc = 0.f;
#pragma unroll 16
    for (int d = 0; d < 64; d++) acc += kp[d * 16] * wq[d * 512];
    Kqb[t] = f2bf(acc);
  } else if (blk < 3072) {
    const int wave = threadIdx.x >> 6;
    const int lane = threadIdx.x & 63;
    const int wgid = (blk - 2048) * 4 + wave;   // [0,4096)
    const int b = wgid >> 9, f = wgid & 511;
    const int l = lane >> 2, c = lane & 3;
    const float* vp = vproj + (size_t)b * 8192 + l * 64 + c * 16;
    const float* wo = Wo + (size_t)f * 512 + c * 16;
#pragma unroll 2
    for (int h = 0; h < 8; h++) {
      const float* v = vp + h * 1024;
      const float* w = wo + h * 64;
      float4 v0 = *(const float4*)v,       w0 = *(const float4*)w;
      float4 v1 = *(const float4*)(v + 4), w1 = *(const float4*)(w + 4);
      float4 v2 = *(const float4*)(v + 8), w2 = *(const float4*)(w + 8);
      float4 v3 = *(const float4*)(v + 12), w3 = *(const float4*)(w + 12);
      float acc = v0.x * w0.x + v0.y * w0.y + v0.z * w0.z + v0.w * w0.w +
                  v1.x * w1.x + v1.y * w1.y + v1.z * w1.z + v1.w * w1.w +
                  v2.x * w2.x + v2.y * w2.y + v2.z * w2.z + v2.w * w2.w +
                  v3.x * w3.x + v3.y * w3.y + v3.z * w3.z + v3.w * w3.w;
      acc += __shfl_xor(acc, 1);
      acc += __shfl_xor(acc, 2);
      if (c == 0) WoVb[(size_t)b * 65536 + (size_t)f * 128 + h * 16 + l] = f2bf(acc);
    }
  } else {
    int t = (blk - 3072) * 256 + threadIdx.x;   // 1024
    int hl = t & 127, b = t >> 7;
    int h = hl >> 4, l = hl & 15;
    const float* kp = kproj + (size_t)b * 8192 + h * 1024 + l;
    const float* q = bq + h * 64;
    float acc = 0.f;
#pragma unroll
    for (int d = 0; d < 64; d++) acc += q[d] * kp[d * 16];
    sb[t] = acc;
  }
}

// ---------------- fused: scores GEMM + softmax + out GEMM ----------------
// v13 = byte-identical r10/r11 body (measured 78us, VGPR 172, WRITE=65536KB).
// NO __launch_bounds__ minimum: r12 re-proved (third time) that any occupancy
// cap makes the allocator jump to a low-VGPR bucket via scratch spills
// (VGPR 84, WRITE +74MB, +22us) instead of shaving registers. Uncapped
// VGPR 172 @ 2 blocks/CU is the allocator's honest optimum for this body.
__global__ __launch_bounds__(256) void fused_attn(
    const float* __restrict__ query, const u16* __restrict__ Kqb,
    const u16* __restrict__ WoVb, const float* __restrict__ sb,
    const float* __restrict__ bo, const int* __restrict__ bidx,
    float* __restrict__ out) {
  __shared__ __align__(16) u16 Bs[2][128 * 64];   // 32 KB: Kq k-slice, dbuf
  __shared__ __align__(16) u16 Ps[64 * 128];      // 16 KB: P, XOR-swizzled
  const int tid = threadIdx.x;
  const int lane = tid & 63;
  const int wave = tid >> 6;
  const int quad = lane >> 4;
  const int l16 = lane & 15;
  const int tileId = blockIdx.x & 511;    // slot in HIGH bit (XCD parity fix)
  const int slot = blockIdx.x >> 9;
  const int m0 = tileId * 64;
  const int bFirst = bidx[m0];
  const int bLast = bidx[m0 + 63];
  if (slot == 1 && bFirst == bLast) return;   // uniform exit, before any barrier
  const int b0 = (slot == 0) ? bFirst : bFirst + 1;
  const int b1 = (slot == 0) ? bFirst : bLast;

  // staging coords (BK=64): 1024 chunks of 16B per 16KB slice; thread owns
  // chunks c_i = tid + i*256 (i=0..3). c -> row=c>>3, physchunk=c&7.
  const int rB = tid >> 3;                       // row of chunk 0
  const int lgB = (tid & 7) ^ (rB & 7);          // global chunk for phys (tid&7)
  const size_t bbase = (size_t)rB * 512 + lgB * 8;   // u16 elems; +i*32*512

  // per-row batch for predicated stores (phase 2: wave covers all 64 rows)
  int rowb[4][4];
#pragma unroll
  for (int mi = 0; mi < 4; mi++)
#pragma unroll
    for (int r = 0; r < 4; r++) rowb[mi][r] = bidx[m0 + mi * 16 + quad * 4 + r];

  // phase-1 A pointer: wave-exclusive row (fp32), quad picks 8-elem sub-slice
  const float* pA = query + (size_t)(m0 + wave * 16 + l16) * 512 + quad * 8;

  for (int bb = b0; bb <= b1; bb++) {
    const u16* Bq = Kqb + (size_t)bb * 65536;

    // prologue: stage k-slice 0 into buf 0; load A slice 0 (fp32)
#pragma unroll
    for (int i = 0; i < 4; i++)
      async16(Bq + bbase + (size_t)i * 32 * 512, &Bs[0][(tid + i * 256) * 8]);
    float4 aC[4];
    aC[0] = *(const float4*)(pA);
    aC[1] = *(const float4*)(pA + 4);
    aC[2] = *(const float4*)(pA + 32);
    aC[3] = *(const float4*)(pA + 36);

    f32x4 acc1[8];
#pragma unroll
    for (int j = 0; j < 8; j++) acc1[j] = (f32x4){0.f, 0.f, 0.f, 0.f};

    for (int t = 0; t < 8; t++) {
      __syncthreads();                     // drains vmcnt -> buf[t&1] + A(t) ready
      const int cur = t & 1;
      if (t < 7) {                         // stage next k-slice; overlaps MFMA below
        const size_t ko = (size_t)(t + 1) * 64;
#pragma unroll
        for (int i = 0; i < 4; i++)
          async16(Bq + bbase + ko + (size_t)i * 32 * 512, &Bs[cur ^ 1][(tid + i * 256) * 8]);
      }
      float4 a0 = aC[0], a1 = aC[1], a2 = aC[2], a3 = aC[3];
      if (t < 7) {                         // prefetch A(t+1)
        const float* p = pA + (t + 1) * 64;
        aC[0] = *(const float4*)(p);
        aC[1] = *(const float4*)(p + 4);
        aC[2] = *(const float4*)(p + 32);
        aC[3] = *(const float4*)(p + 36);
      }
      short8 af[2];
      af[0][0] = (short)f2bf(a0.x); af[0][1] = (short)f2bf(a0.y);
      af[0][2] = (short)f2bf(a0.z); af[0][3] = (short)f2bf(a0.w);
      af[0][4] = (short)f2bf(a1.x); af[0][5] = (short)f2bf(a1.y);
      af[0][6] = (short)f2bf(a1.z); af[0][7] = (short)f2bf(a1.w);
      af[1][0] = (short)f2bf(a2.x); af[1][1] = (short)f2bf(a2.y);
      af[1][2] = (short)f2bf(a2.z); af[1][3] = (short)f2bf(a2.w);
      af[1][4] = (short)f2bf(a3.x); af[1][5] = (short)f2bf(a3.y);
      af[1][6] = (short)f2bf(a3.z); af[1][7] = (short)f2bf(a3.w);
      __builtin_amdgcn_s_setprio(1);
#pragma unroll
      for (int kk = 0; kk < 2; kk++) {
#pragma unroll
        for (int ni = 0; ni < 8; ni++) {
          const int rw = ni * 16 + l16;
          const int phys = (kk * 4 + quad) ^ (rw & 7);
          short8 bfr = *(const short8*)&Bs[cur][rw * 64 + phys * 8];
          acc1[ni] = __builtin_amdgcn_mfma_f32_16x16x32_bf16(af[kk], bfr, acc1[ni], 0, 0, 0);
        }
      }
      __builtin_amdgcn_s_setprio(0);
    }

    // ---- softmax over each head's 16 l-cols (16-lane shfl), P -> LDS ----
    float sbv[8];
#pragma unroll
    for (int ni = 0; ni < 8; ni++) sbv[ni] = sb[bb * 128 + ni * 16 + l16];
#pragma unroll
    for (int r = 0; r < 4; r++) {
      const int row = wave * 16 + quad * 4 + r;   // wave-exclusive rows
#pragma unroll
      for (int ni = 0; ni < 8; ni++) {
        float v = acc1[ni][r] + sbv[ni];
        float mx = v;
        mx = fmaxf(mx, __shfl_xor(mx, 1));
        mx = fmaxf(mx, __shfl_xor(mx, 2));
        mx = fmaxf(mx, __shfl_xor(mx, 4));
        mx = fmaxf(mx, __shfl_xor(mx, 8));
        float ev = __expf((v - mx) * 0.125f);   // scale = D^-0.5
        float s = ev;
        s += __shfl_xor(s, 1);
        s += __shfl_xor(s, 2);
        s += __shfl_xor(s, 4);
        s += __shfl_xor(s, 8);
        const int col = ni * 16 + l16;
        Ps[row * 128 + (((col >> 3) ^ (row & 7)) << 3) + (col & 7)] = f2bf(ev / s);
      }
    }
    __syncthreads();   // all P stripes visible

    // ---- phase 2: out[64,512] = P x WoV[bb]^T; wave owns 128 f-cols ----
    const u16* Wv = WoVb + (size_t)bb * 65536;
#pragma unroll
    for (int h2 = 0; h2 < 2; h2++) {
      const int f0 = wave * 128 + h2 * 64;
      f32x4 acc2[4][4];
#pragma unroll
      for (int i = 0; i < 4; i++)
#pragma unroll
        for (int j = 0; j < 4; j++) acc2[i][j] = (f32x4){0.f, 0.f, 0.f, 0.f};
#pragma unroll
      for (int kk = 0; kk < 4; kk++) {
        short8 paf[4], bf2[4];
#pragma unroll
        for (int mi = 0; mi < 4; mi++) {
          const int row = mi * 16 + l16;
          paf[mi] = *(const short8*)&Ps[row * 128 + (((kk * 4 + quad) ^ (row & 7)) << 3)];
        }
#pragma unroll
        for (int ni = 0; ni < 4; ni++) {
          const int fr = f0 + ni * 16 + l16;
          bf2[ni] = *(const short8*)(Wv + (size_t)fr * 128 + kk * 32 + quad * 8);
        }
        __builtin_amdgcn_s_setprio(1);
#pragma unroll
        for (int mi = 0; mi < 4; mi++)
#pragma unroll
          for (int ni = 0; ni < 4; ni++)
            acc2[mi][ni] = __builtin_amdgcn_mfma_f32_16x16x32_bf16(paf[mi], bf2[ni], acc2[mi][ni], 0, 0, 0);
        __builtin_amdgcn_s_setprio(0);
      }
      float bov[4];
#pragma unroll
      for (int ni = 0; ni < 4; ni++) bov[ni] = bo[f0 + ni * 16 + l16];
#pragma unroll
      for (int mi = 0; mi < 4; mi++)
#pragma unroll
        for (int r = 0; r < 4; r++) {
          if (rowb[mi][r] == bb) {
            const size_t row = m0 + mi * 16 + quad * 4 + r;
#pragma unroll
            for (int ni = 0; ni < 4; ni++)
              out[row * 512 + f0 + ni * 16 + l16] = acc2[mi][ni][r] + bov[ni];
          }
        }
    }
    __syncthreads();   // Ps/Bs safe to overwrite next bb
  }
}

extern "C" void kernel_launch(void* const* d_in, const int* in_sizes, int n_in,
                              void* d_out, int out_size, void* d_ws, size_t ws_size,
                              hipStream_t stream) {
  const float* query = (const float*)d_in[0];
  const float* keyt = (const float*)d_in[1];
  const float* valt = (const float*)d_in[2];
  const int* bidx = (const int*)d_in[3];
  // d_in[4] = batch_size (scalar, fixed = 8)
  const float* Wq = (const float*)d_in[5];
  const float* bq = (const float*)d_in[6];
  const float* Wk = (const float*)d_in[7];
  const float* bk = (const float*)d_in[8];
  const float* Wv = (const float*)d_in[9];
  const float* bv = (const float*)d_in[10];
  const float* Wo = (const float*)d_in[11];
  const float* bo = (const float*)d_in[12];
  float* out = (float*)d_out;

  // workspace layout (bytes)
  unsigned char* w = (unsigned char*)d_ws;
  float* kproj = (float*)(w + 41943040ull);   //    262,144: [B,H,D,L]
  float* vproj = (float*)(w + 42205184ull);   //    262,144: [B,H,L,D]
  u16* Kqb = (u16*)(w + 42467328ull);         //  1,048,576: [B,128,512] bf16
  u16* WoVb = (u16*)(w + 43515904ull);        //  1,048,576: [B,512,128] bf16
  float* sb = (float*)(w + 44564480ull);      //      4,096: [B,128]

  // 1) K/V projections (coalesced wave-per-row, 2048 blocks)
  kvproj_kernel<<<2048, 256, 0, stream>>>(keyt, valt, Wk, bk, Wv, bv, kproj, vproj);

  // 2) fold Wq through k, Wo through v, and sb — one launch
  build_all<<<3076, 256, 0, stream>>>(kproj, vproj, Wq, bq, Wo, Kqb, WoVb, sb);

  // 3) fused: fp32 query -> scores -> softmax -> out (slot in HIGH bit)
  fused_attn<<<N_TOKENS / 64 * 2, 256, 0, stream>>>(query, Kqb, WoVb, sb, bo, bidx, out);
}